// Round 2
// baseline (462.368 us; speedup 1.0000x reference)
//
#include <hip/hip_runtime.h>
#include <hip/hip_bf16.h>
#include <math.h>

// Problem dims (fixed)
#define B 4
#define S 1024
#define E 512
#define H 64
#define DK 8
#define FFN 2048
#define BS (B*S)          // 4096 tokens

// ---------------------------------------------------------------------------
// K1: attention per head, cos(x+phi) fused. Whole head's 1024x8 tile in LDS.
// grid = 1024 blocks (4 per head), 256 threads, 1 query row per thread.
// Plain softmax (|score| <= sqrt(8), exp never overflows).
// ---------------------------------------------------------------------------
__global__ __launch_bounds__(256) void attn_kernel(const float* __restrict__ x,
                                                   const float* __restrict__ phi,
                                                   float* __restrict__ attn_out) {
    int head = blockIdx.x >> 2;          // 0..255 = b*64+h
    int qblk = blockIdx.x & 3;
    int b = head >> 6, h = head & 63;

    float ph[DK];
    #pragma unroll
    for (int d = 0; d < DK; d++) ph[d] = phi[d];   // broadcast loads

    __shared__ float kv[S * DK];         // 32 KB
    for (int r = threadIdx.x; r < S; r += 256) {
        const float* xp = x + ((size_t)(b * S + r)) * E + h * DK;   // 32B-aligned
        float4 u = *(const float4*)xp;
        float4 v = *(const float4*)(xp + 4);
        float* k = kv + r * DK;
        k[0] = cosf(u.x + ph[0]); k[1] = cosf(u.y + ph[1]);
        k[2] = cosf(u.z + ph[2]); k[3] = cosf(u.w + ph[3]);
        k[4] = cosf(v.x + ph[4]); k[5] = cosf(v.y + ph[5]);
        k[6] = cosf(v.z + ph[6]); k[7] = cosf(v.w + ph[7]);
    }
    __syncthreads();

    int q = qblk * 256 + threadIdx.x;
    float qv[DK];
    #pragma unroll
    for (int d = 0; d < DK; d++) qv[d] = kv[q * DK + d] * 0.35355339059327373f; // 1/sqrt(8)

    float o[DK] = {0.f,0.f,0.f,0.f,0.f,0.f,0.f,0.f};
    float ssum = 0.f;
    for (int k = 0; k < S; k++) {
        float sc = 0.f;
        #pragma unroll
        for (int d = 0; d < DK; d++) sc = fmaf(qv[d], kv[k * DK + d], sc);  // broadcast reads
        float p = __expf(sc);
        ssum += p;
        #pragma unroll
        for (int d = 0; d < DK; d++) o[d] = fmaf(p, kv[k * DK + d], o[d]);
    }
    float inv = 1.f / ssum;
    float* op = attn_out + ((size_t)(b * S + q)) * E + h * DK;
    float4 o0 = make_float4(o[0]*inv, o[1]*inv, o[2]*inv, o[3]*inv);
    float4 o1 = make_float4(o[4]*inv, o[5]*inv, o[6]*inv, o[7]*inv);
    *(float4*)op = o0;
    *(float4*)(op + 4) = o1;
}

// ---------------------------------------------------------------------------
// K2: tiled fp32 GEMM  C[M,N] = A[M,K] @ Bm[K,N] + bias[N]
// BM=BN=64, BK=32, 256 threads, 4x4 per thread.
// ---------------------------------------------------------------------------
#define BM 64
#define BN 64
#define BK 32
__global__ __launch_bounds__(256) void gemm_kernel(const float* __restrict__ A,
                                                   const float* __restrict__ Bm,
                                                   const float* __restrict__ bias,
                                                   float* __restrict__ C,
                                                   int M, int N, int K) {
    __shared__ float As[BM][BK + 1];     // +1 pad: conflict-free column reads
    __shared__ float Bs[BK][BN];
    int tid = threadIdx.x;
    int tx = tid & 15, ty = tid >> 4;
    int m0 = blockIdx.x * BM, n0 = blockIdx.y * BN;

    float acc[4][4] = {};
    for (int kb = 0; kb < K; kb += BK) {
        #pragma unroll
        for (int i = 0; i < 2; i++) {
            int j = tid + i * 256;
            int r = j >> 3, c4 = (j & 7) << 2;
            float4 v = *(const float4*)(A + (size_t)(m0 + r) * K + kb + c4);
            As[r][c4] = v.x; As[r][c4 + 1] = v.y; As[r][c4 + 2] = v.z; As[r][c4 + 3] = v.w;
        }
        #pragma unroll
        for (int i = 0; i < 2; i++) {
            int j = tid + i * 256;
            int r = j >> 4, c4 = (j & 15) << 2;
            *(float4*)(&Bs[r][c4]) = *(const float4*)(Bm + (size_t)(kb + r) * N + n0 + c4);
        }
        __syncthreads();
        #pragma unroll
        for (int kk = 0; kk < BK; kk++) {
            float a[4];
            #pragma unroll
            for (int i = 0; i < 4; i++) a[i] = As[ty * 4 + i][kk];
            float4 bv = *(float4*)(&Bs[kk][tx * 4]);
            float bb[4] = {bv.x, bv.y, bv.z, bv.w};
            #pragma unroll
            for (int i = 0; i < 4; i++)
                #pragma unroll
                for (int j2 = 0; j2 < 4; j2++)
                    acc[i][j2] = fmaf(a[i], bb[j2], acc[i][j2]);
        }
        __syncthreads();
    }
    #pragma unroll
    for (int i = 0; i < 4; i++) {
        int row = m0 + ty * 4 + i;
        #pragma unroll
        for (int j2 = 0; j2 < 4; j2++) {
            int col = n0 + tx * 4 + j2;
            C[(size_t)row * N + col] = acc[i][j2] + bias[col];
        }
    }
}

// ---------------------------------------------------------------------------
// K4: fused FFN GEMM  C[BS,E] = relu(qout@W1 + b1) @ W2 + b2
// The 64x32 h-tile is recomputed in LDS from qout (K1=8) each K-step.
// ---------------------------------------------------------------------------
__global__ __launch_bounds__(256) void ffn_gemm_kernel(const float* __restrict__ qout,
                                                       const float* __restrict__ W1,
                                                       const float* __restrict__ b1,
                                                       const float* __restrict__ W2,
                                                       const float* __restrict__ b2,
                                                       float* __restrict__ C) {
    __shared__ float As[BM][BK + 1];     // h tile
    __shared__ float Bs[BK][BN];         // W2 tile
    __shared__ float qs[BM * DK];        // qout rows for this M-block
    __shared__ float w1s[DK][BK];
    __shared__ float b1s[BK];
    int tid = threadIdx.x;
    int tx = tid & 15, ty = tid >> 4;
    int m0 = blockIdx.x * BM, n0 = blockIdx.y * BN;

    for (int i = tid; i < BM * DK; i += 256) qs[i] = qout[m0 * DK + i];

    float acc[4][4] = {};
    for (int kb = 0; kb < FFN; kb += BK) {
        { int i2 = tid >> 5, c = tid & 31; w1s[i2][c] = W1[i2 * FFN + kb + c]; }
        if (tid < BK) b1s[tid] = b1[kb + tid];
        #pragma unroll
        for (int i = 0; i < 2; i++) {
            int j = tid + i * 256;
            int r = j >> 4, c4 = (j & 15) << 2;
            *(float4*)(&Bs[r][c4]) = *(const float4*)(W2 + (size_t)(kb + r) * E + n0 + c4);
        }
        __syncthreads();                 // qs/w1s/b1s/Bs ready
        // h tile: 64x32, 8 elems/thread
        #pragma unroll
        for (int e = 0; e < 8; e++) {
            int idx = tid + e * 256;
            int r = idx >> 5, c = idx & 31;
            float a0 = b1s[c];
            #pragma unroll
            for (int i = 0; i < DK; i++) a0 = fmaf(qs[r * DK + i], w1s[i][c], a0);
            As[r][c] = fmaxf(a0, 0.f);
        }
        __syncthreads();                 // As ready
        #pragma unroll
        for (int kk = 0; kk < BK; kk++) {
            float a[4];
            #pragma unroll
            for (int i = 0; i < 4; i++) a[i] = As[ty * 4 + i][kk];
            float4 bv = *(float4*)(&Bs[kk][tx * 4]);
            float bb[4] = {bv.x, bv.y, bv.z, bv.w};
            #pragma unroll
            for (int i = 0; i < 4; i++)
                #pragma unroll
                for (int j2 = 0; j2 < 4; j2++)
                    acc[i][j2] = fmaf(a[i], bb[j2], acc[i][j2]);
        }
        __syncthreads();                 // before next iter overwrites tiles
    }
    #pragma unroll
    for (int i = 0; i < 4; i++) {
        int row = m0 + ty * 4 + i;
        #pragma unroll
        for (int j2 = 0; j2 < 4; j2++) {
            int col = n0 + tx * 4 + j2;
            C[(size_t)row * E + col] = acc[i][j2] + b2[col];
        }
    }
}

// ---------------------------------------------------------------------------
// K3/K5: LayerNorm over E=512:  out = LN(a + r) * g + be
// One block per token, 256 threads, 2 elems/thread. `a`/`out` may alias
// (in-place per token; reads precede writes across the barrier) -> no restrict.
// Optional epilogue: qout[t,i] = cos(out[t,i]) * cos(theta[i]) for i<8.
// ---------------------------------------------------------------------------
__global__ __launch_bounds__(256) void ln_kernel(const float* a,
                                                 const float* r,
                                                 const float* __restrict__ g,
                                                 const float* __restrict__ be,
                                                 float* out,
                                                 float* __restrict__ qout,
                                                 const float* __restrict__ theta) {
    int t = blockIdx.x, tid = threadIdx.x;
    size_t base = (size_t)t * E;
    float v0 = a[base + tid]       + r[base + tid];
    float v1 = a[base + tid + 256] + r[base + tid + 256];
    float s  = v0 + v1;
    float sq = v0 * v0 + v1 * v1;
    #pragma unroll
    for (int off = 32; off > 0; off >>= 1) {
        s  += __shfl_down(s, off);
        sq += __shfl_down(sq, off);
    }
    __shared__ float ls[4], lq[4];
    int wave = tid >> 6, lane = tid & 63;
    if (lane == 0) { ls[wave] = s; lq[wave] = sq; }
    __syncthreads();
    if (tid == 0) {
        float SS = ls[0] + ls[1] + ls[2] + ls[3];
        float QQ = lq[0] + lq[1] + lq[2] + lq[3];
        float mu = SS * (1.f / E);
        float var = QQ * (1.f / E) - mu * mu;
        ls[0] = mu;
        lq[0] = rsqrtf(var + 1e-5f);
    }
    __syncthreads();
    float mu = ls[0], rstd = lq[0];
    float y0 = (v0 - mu) * rstd * g[tid]       + be[tid];
    float y1 = (v1 - mu) * rstd * g[tid + 256] + be[tid + 256];
    out[base + tid]       = y0;
    out[base + tid + 256] = y1;
    if (qout != nullptr && tid < DK) {
        qout[t * DK + tid] = cosf(y0) * cosf(theta[tid]);
    }
}

// ---------------------------------------------------------------------------
// launch — ws usage: 8 MB proj/ffn buffer + 128 KB qout = 8.13 MB total.
// d_out doubles as scratch for attn_out and x1 (final write re-validated).
// ---------------------------------------------------------------------------
extern "C" void kernel_launch(void* const* d_in, const int* in_sizes, int n_in,
                              void* d_out, int out_size, void* d_ws, size_t ws_size,
                              hipStream_t stream) {
    const float* x     = (const float*)d_in[0];
    const float* phi   = (const float*)d_in[1];
    const float* Wc    = (const float*)d_in[2];
    const float* bc    = (const float*)d_in[3];
    const float* theta = (const float*)d_in[4];
    const float* W1    = (const float*)d_in[5];
    const float* b1    = (const float*)d_in[6];
    const float* W2    = (const float*)d_in[7];
    const float* b2    = (const float*)d_in[8];
    const float* g1    = (const float*)d_in[9];
    const float* be1   = (const float*)d_in[10];
    const float* g2    = (const float*)d_in[11];
    const float* be2   = (const float*)d_in[12];
    float* out = (float*)d_out;

    float* ws = (float*)d_ws;
    const size_t NTOK_E = (size_t)BS * E;        // 2,097,152 floats (8 MB)
    float* proj = ws;                            // combine-GEMM out, later ffn_out
    float* qout = ws + NTOK_E;                   // [BS,8]  128 KB

    // 1. attention (cos fused) -> d_out (scratch)
    attn_kernel<<<B * H * 4, 256, 0, stream>>>(x, phi, out);
    // 2. proj = attn_out @ Wc + bc
    gemm_kernel<<<dim3(BS / BM, E / BN), 256, 0, stream>>>(out, Wc, bc, proj, BS, E, E);
    // 3. x1 = LN(x + proj) -> d_out (attn_out dead); qout epilogue
    ln_kernel<<<BS, 256, 0, stream>>>(x, proj, g1, be1, out, qout, theta);
    // 4. ffn_out = relu(qout@W1+b1) @ W2 + b2 -> proj buffer (dead)
    ffn_gemm_kernel<<<dim3(BS / BM, E / BN), 256, 0, stream>>>(qout, W1, b1, W2, b2, proj);
    // 5. out = LN(x1 + ffn_out), in-place on d_out
    ln_kernel<<<BS, 256, 0, stream>>>(out, proj, g2, be2, out, nullptr, nullptr);
}

// Round 3
// 318.654 us; speedup vs baseline: 1.4510x; 1.4510x over previous
//
#include <hip/hip_runtime.h>
#include <hip/hip_bf16.h>
#include <math.h>

// Problem dims (fixed)
#define B 4
#define S 1024
#define E 512
#define H 64
#define DK 8
#define FFN 2048
#define BS (B*S)          // 4096 tokens

typedef __attribute__((ext_vector_type(8))) short short8;   // 8 bf16 (4 VGPRs)
typedef __attribute__((ext_vector_type(4))) float float4a;  // MFMA C/D frag

// fp32 -> bf16 round-to-nearest-even
__device__ __forceinline__ unsigned short f2bf(float f) {
    unsigned u = __builtin_bit_cast(unsigned, f);
    u = (u + 0x7fffu + ((u >> 16) & 1u)) >> 16;
    return (unsigned short)u;
}
__device__ __forceinline__ float bf2f(unsigned short h) {
    unsigned u = ((unsigned)h) << 16;
    return __builtin_bit_cast(float, u);
}

// ---------------------------------------------------------------------------
// K0: convert Wc[512][512] and W2[2048][512] (fp32, k-major) to bf16
// transposed Wt[n][k] (k-contiguous rows) so GEMM B-fragments are 16B loads.
// 64x64 tiles through LDS. Blocks 0..63 -> Wc, 64..319 -> W2.
// ---------------------------------------------------------------------------
__global__ __launch_bounds__(256) void convert_kernel(const float* __restrict__ Wc,
                                                      const float* __restrict__ W2,
                                                      unsigned short* __restrict__ Wct,
                                                      unsigned short* __restrict__ W2t) {
    int bid = blockIdx.x;
    const float* src; unsigned short* dst; int Kdim, kt, nt;
    if (bid < 64) { src = Wc; dst = Wct; Kdim = 512;  kt = bid >> 3;        nt = bid & 7; }
    else          { src = W2; dst = W2t; Kdim = 2048; kt = (bid - 64) >> 3; nt = (bid - 64) & 7; }
    int k0 = kt * 64, n0 = nt * 64;
    __shared__ float Ls[64][65];
    int tid = threadIdx.x;
    int rr = tid >> 4, c4 = (tid & 15) * 4;
    #pragma unroll
    for (int it = 0; it < 4; it++) {
        int k = rr + it * 16;
        float4 v = *(const float4*)(src + (size_t)(k0 + k) * 512 + n0 + c4);
        Ls[k][c4] = v.x; Ls[k][c4 + 1] = v.y; Ls[k][c4 + 2] = v.z; Ls[k][c4 + 3] = v.w;
    }
    __syncthreads();
    int n = tid >> 2, koff = (tid & 3) * 16;
    short8 o0, o1;
    #pragma unroll
    for (int j = 0; j < 8; j++) {
        o0[j] = (short)f2bf(Ls[koff + j][n]);
        o1[j] = (short)f2bf(Ls[koff + 8 + j][n]);
    }
    unsigned short* p = dst + (size_t)(n0 + n) * Kdim + k0 + koff;
    *(short8*)p = o0;
    *(short8*)(p + 8) = o1;
}

// ---------------------------------------------------------------------------
// K1: attention per head, cos(x+phi) fused, bf16 output (feeds MFMA GEMM).
// grid = 1024 blocks (4 per head), 256 threads, 1 query row per thread.
// ---------------------------------------------------------------------------
__global__ __launch_bounds__(256) void attn_kernel(const float* __restrict__ x,
                                                   const float* __restrict__ phi,
                                                   unsigned short* __restrict__ attn_bf) {
    int head = blockIdx.x >> 2;          // 0..255 = b*64+h
    int qblk = blockIdx.x & 3;
    int b = head >> 6, h = head & 63;

    float ph[DK];
    #pragma unroll
    for (int d = 0; d < DK; d++) ph[d] = phi[d];

    __shared__ float kv[S * DK];         // 32 KB
    for (int r = threadIdx.x; r < S; r += 256) {
        const float* xp = x + ((size_t)(b * S + r)) * E + h * DK;
        float4 u = *(const float4*)xp;
        float4 v = *(const float4*)(xp + 4);
        float* k = kv + r * DK;
        k[0] = cosf(u.x + ph[0]); k[1] = cosf(u.y + ph[1]);
        k[2] = cosf(u.z + ph[2]); k[3] = cosf(u.w + ph[3]);
        k[4] = cosf(v.x + ph[4]); k[5] = cosf(v.y + ph[5]);
        k[6] = cosf(v.z + ph[6]); k[7] = cosf(v.w + ph[7]);
    }
    __syncthreads();

    int q = qblk * 256 + threadIdx.x;
    float qv[DK];
    #pragma unroll
    for (int d = 0; d < DK; d++) qv[d] = kv[q * DK + d] * 0.35355339059327373f;

    float o[DK] = {0.f,0.f,0.f,0.f,0.f,0.f,0.f,0.f};
    float ssum = 0.f;
    for (int k = 0; k < S; k++) {
        float sc = 0.f;
        #pragma unroll
        for (int d = 0; d < DK; d++) sc = fmaf(qv[d], kv[k * DK + d], sc);
        float p = __expf(sc);
        ssum += p;
        #pragma unroll
        for (int d = 0; d < DK; d++) o[d] = fmaf(p, kv[k * DK + d], o[d]);
    }
    float inv = 1.f / ssum;
    unsigned short* op = attn_bf + ((size_t)(b * S + q)) * E + h * DK;
    short8 ov;
    #pragma unroll
    for (int d = 0; d < DK; d++) ov[d] = (short)f2bf(o[d] * inv);
    *(short8*)op = ov;
}

// ---------------------------------------------------------------------------
// K2: combine-heads GEMM via MFMA, no LDS, no barriers.
// C[4096,512] = A[4096,512]bf16 @ Wc + bc, Bt = Wct[n][k] bf16.
// BM=64 BN=128 BK=32, 256 thr = 4 waves, wave w -> m-tile w x 8 n-tiles.
// ---------------------------------------------------------------------------
__global__ __launch_bounds__(256) void combine_mfma(const unsigned short* __restrict__ A,
                                                    const unsigned short* __restrict__ Bt,
                                                    const float* __restrict__ bias,
                                                    unsigned short* __restrict__ Cbf) {
    int tid = threadIdx.x;
    int w = tid >> 6, lane = tid & 63;
    int row = lane & 15, g = lane >> 4, g8 = g * 8;
    int m0 = blockIdx.x * 64, n0 = blockIdx.y * 128;
    int mbase = m0 + w * 16;

    float4a acc[8];
    #pragma unroll
    for (int nt = 0; nt < 8; nt++) acc[nt] = 0.f;

    const unsigned short* ap = A + (size_t)(mbase + row) * 512 + g8;
    for (int kb = 0; kb < 512; kb += 32) {
        short8 af = *(const short8*)(ap + kb);
        #pragma unroll
        for (int nt = 0; nt < 8; nt++) {
            short8 bf = *(const short8*)(Bt + (size_t)(n0 + nt * 16 + row) * 512 + kb + g8);
            acc[nt] = __builtin_amdgcn_mfma_f32_16x16x32_bf16(af, bf, acc[nt], 0, 0, 0);
        }
    }
    int crow = mbase + g * 4;            // C/D: row=(l>>4)*4+r, col=l&15
    #pragma unroll
    for (int nt = 0; nt < 8; nt++) {
        int col = n0 + nt * 16 + row;
        float bb = bias[col];
        #pragma unroll
        for (int r = 0; r < 4; r++)
            Cbf[(size_t)(crow + r) * 512 + col] = f2bf(acc[nt][r] + bb);
    }
}

// ---------------------------------------------------------------------------
// K4: FFN via MFMA: C[4096,512] = relu(qout@W1+b1) @ W2 + b2.
// Each lane computes its OWN A-frag h-values in registers (h[l&15][g*8+j])
// from LDS-resident W1 (broadcast reads) -> no LDS round-trip for h,
// single barrier, K-loop barrier-free. W2t[n][k] bf16 B-frags from global.
// ---------------------------------------------------------------------------
__global__ __launch_bounds__(256) void ffn_mfma(const float* __restrict__ qout,
                                                const float* __restrict__ W1,
                                                const float* __restrict__ b1,
                                                const unsigned short* __restrict__ W2t,
                                                const float* __restrict__ b2,
                                                unsigned short* __restrict__ Cbf) {
    __shared__ float w1s[8 * FFN];       // 64 KB
    __shared__ float b1s[FFN];           // 8 KB
    __shared__ float qs[64 * DK];        // 2 KB
    int tid = threadIdx.x;
    {
        const float4* s = (const float4*)W1; float4* d = (float4*)w1s;
        for (int i = tid; i < 8 * FFN / 4; i += 256) d[i] = s[i];
        const float4* sb = (const float4*)b1; float4* db = (float4*)b1s;
        for (int i = tid; i < FFN / 4; i += 256) db[i] = sb[i];
    }
    int m0 = blockIdx.x * 64, n0 = blockIdx.y * 128;
    if (tid < 128) ((float4*)qs)[tid] = ((const float4*)(qout + (size_t)m0 * DK))[tid];
    __syncthreads();

    int w = tid >> 6, lane = tid & 63;
    int row = lane & 15, g = lane >> 4, g8 = g * 8;
    float qv[8];
    #pragma unroll
    for (int i = 0; i < 8; i++) qv[i] = qs[(w * 16 + row) * 8 + i];

    float4a acc[8];
    #pragma unroll
    for (int nt = 0; nt < 8; nt++) acc[nt] = 0.f;

    for (int kb = 0; kb < FFN; kb += 32) {
        float hv[8];
        const float* bp = &b1s[kb + g8];
        #pragma unroll
        for (int j = 0; j < 8; j++) hv[j] = bp[j];
        #pragma unroll
        for (int i = 0; i < 8; i++) {
            const float* wp = &w1s[i * FFN + kb + g8];
            float qi = qv[i];
            #pragma unroll
            for (int j = 0; j < 8; j++) hv[j] = fmaf(qi, wp[j], hv[j]);
        }
        short8 af;
        #pragma unroll
        for (int j = 0; j < 8; j++) af[j] = (short)f2bf(fmaxf(hv[j], 0.f));
        #pragma unroll
        for (int nt = 0; nt < 8; nt++) {
            short8 bf = *(const short8*)(W2t + (size_t)(n0 + nt * 16 + row) * FFN + kb + g8);
            acc[nt] = __builtin_amdgcn_mfma_f32_16x16x32_bf16(af, bf, acc[nt], 0, 0, 0);
        }
    }
    int crow = m0 + w * 16 + g * 4;
    #pragma unroll
    for (int nt = 0; nt < 8; nt++) {
        int col = n0 + nt * 16 + row;
        float bb = b2[col];
        #pragma unroll
        for (int r = 0; r < 4; r++)
            Cbf[(size_t)(crow + r) * 512 + col] = f2bf(acc[nt][r] + bb);
    }
}

// ---------------------------------------------------------------------------
// K3/K5: LayerNorm over E=512, residual in bf16: out = LN(a + r) * g + be.
// Optional epilogue: qout[t,i] = cos(out[t,i]) * cos(theta[i]) for i<8.
// a/out may alias (in-place per token).
// ---------------------------------------------------------------------------
__global__ __launch_bounds__(256) void ln_kernel(const float* a,
                                                 const unsigned short* __restrict__ r,
                                                 const float* __restrict__ g,
                                                 const float* __restrict__ be,
                                                 float* out,
                                                 float* __restrict__ qout,
                                                 const float* __restrict__ theta) {
    int t = blockIdx.x, tid = threadIdx.x;
    size_t base = (size_t)t * E;
    float v0 = a[base + tid]       + bf2f(r[base + tid]);
    float v1 = a[base + tid + 256] + bf2f(r[base + tid + 256]);
    float s  = v0 + v1;
    float sq = v0 * v0 + v1 * v1;
    #pragma unroll
    for (int off = 32; off > 0; off >>= 1) {
        s  += __shfl_down(s, off);
        sq += __shfl_down(sq, off);
    }
    __shared__ float ls[4], lq[4];
    int wave = tid >> 6, lane = tid & 63;
    if (lane == 0) { ls[wave] = s; lq[wave] = sq; }
    __syncthreads();
    if (tid == 0) {
        float SS = ls[0] + ls[1] + ls[2] + ls[3];
        float QQ = lq[0] + lq[1] + lq[2] + lq[3];
        float mu = SS * (1.f / E);
        float var = QQ * (1.f / E) - mu * mu;
        ls[0] = mu;
        lq[0] = rsqrtf(var + 1e-5f);
    }
    __syncthreads();
    float mu = ls[0], rstd = lq[0];
    float y0 = (v0 - mu) * rstd * g[tid]       + be[tid];
    float y1 = (v1 - mu) * rstd * g[tid + 256] + be[tid + 256];
    out[base + tid]       = y0;
    out[base + tid + 256] = y1;
    if (qout != nullptr && tid < DK) {
        qout[t * DK + tid] = cosf(y0) * cosf(theta[tid]);
    }
}

// ---------------------------------------------------------------------------
// launch — ws usage: proj_bf 4MB + Wct 0.5MB + W2t 2MB + qout 128KB = 6.63 MB
// (under the 8.13 MB proven-safe budget). d_out doubles as scratch:
// attn_bf (first 4MB) then x1 (full 8MB fp32), final LN2 in-place.
// ---------------------------------------------------------------------------
extern "C" void kernel_launch(void* const* d_in, const int* in_sizes, int n_in,
                              void* d_out, int out_size, void* d_ws, size_t ws_size,
                              hipStream_t stream) {
    const float* x     = (const float*)d_in[0];
    const float* phi   = (const float*)d_in[1];
    const float* Wc    = (const float*)d_in[2];
    const float* bc    = (const float*)d_in[3];
    const float* theta = (const float*)d_in[4];
    const float* W1    = (const float*)d_in[5];
    const float* b1    = (const float*)d_in[6];
    const float* W2    = (const float*)d_in[7];
    const float* b2    = (const float*)d_in[8];
    const float* g1    = (const float*)d_in[9];
    const float* be1   = (const float*)d_in[10];
    const float* g2    = (const float*)d_in[11];
    const float* be2   = (const float*)d_in[12];
    float* out = (float*)d_out;

    float* ws = (float*)d_ws;
    unsigned short* proj_bf = (unsigned short*)ws;                       // [4096][512] bf16
    unsigned short* Wct     = (unsigned short*)(ws + 1048576);           // [512][512] bf16
    unsigned short* W2t     = (unsigned short*)(ws + 1048576 + 131072);  // [512][2048] bf16
    float*          qout    = ws + 1048576 + 131072 + 524288;            // [4096][8] fp32
    unsigned short* attn_bf = (unsigned short*)d_out;                    // [4096][512] bf16

    // 0. weights -> bf16 transposed
    convert_kernel<<<320, 256, 0, stream>>>(Wc, W2, Wct, W2t);
    // 1. attention (cos fused) -> bf16
    attn_kernel<<<B * H * 4, 256, 0, stream>>>(x, phi, attn_bf);
    // 2. proj = attn @ Wc + bc (MFMA) -> bf16
    combine_mfma<<<dim3(64, 4), 256, 0, stream>>>(attn_bf, Wct, bc, proj_bf);
    // 3. x1 = LN(x + proj) -> d_out fp32; qout epilogue
    ln_kernel<<<BS, 256, 0, stream>>>(x, proj_bf, g1, be1, out, qout, theta);
    // 4. ffn_out = relu(qout@W1+b1) @ W2 + b2 (MFMA) -> proj_bf region (dead)
    ffn_mfma<<<dim3(64, 4), 256, 0, stream>>>(qout, W1, b1, W2t, b2, proj_bf);
    // 5. out = LN(x1 + ffn_out), in-place on d_out
    ln_kernel<<<BS, 256, 0, stream>>>(out, proj_bf, g2, be2, out, nullptr, nullptr);
}

// Round 4
// 291.029 us; speedup vs baseline: 1.5887x; 1.0949x over previous
//
#include <hip/hip_runtime.h>
#include <hip/hip_bf16.h>
#include <math.h>

// Problem dims (fixed)
#define B 4
#define S 1024
#define E 512
#define H 64
#define DK 8
#define FFN 2048
#define BS (B*S)          // 4096 tokens

typedef __attribute__((ext_vector_type(8))) short short8;   // 8 bf16 (4 VGPRs)
typedef __attribute__((ext_vector_type(4))) float float4a;  // MFMA C/D frag

// fp32 -> bf16 round-to-nearest-even
__device__ __forceinline__ unsigned short f2bf(float f) {
    unsigned u = __builtin_bit_cast(unsigned, f);
    u = (u + 0x7fffu + ((u >> 16) & 1u)) >> 16;
    return (unsigned short)u;
}
// fp32 -> bf16 truncate (1 op; used for P where num/denom bias cancels)
__device__ __forceinline__ unsigned short f2bf_trunc(float f) {
    return (unsigned short)(__builtin_bit_cast(unsigned, f) >> 16);
}
__device__ __forceinline__ float bf2f(unsigned short h) {
    unsigned u = ((unsigned)h) << 16;
    return __builtin_bit_cast(float, u);
}

// ---------------------------------------------------------------------------
// K0: convert Wc[512][512] and W2[2048][512] (fp32, k-major) to bf16
// transposed Wt[n][k] (k-contiguous) so GEMM B-fragments are 16B loads.
// ---------------------------------------------------------------------------
__global__ __launch_bounds__(256) void convert_kernel(const float* __restrict__ Wc,
                                                      const float* __restrict__ W2,
                                                      unsigned short* __restrict__ Wct,
                                                      unsigned short* __restrict__ W2t) {
    int bid = blockIdx.x;
    const float* src; unsigned short* dst; int Kdim, kt, nt;
    if (bid < 64) { src = Wc; dst = Wct; Kdim = 512;  kt = bid >> 3;        nt = bid & 7; }
    else          { src = W2; dst = W2t; Kdim = 2048; kt = (bid - 64) >> 3; nt = (bid - 64) & 7; }
    int k0 = kt * 64, n0 = nt * 64;
    __shared__ float Ls[64][65];
    int tid = threadIdx.x;
    int rr = tid >> 4, c4 = (tid & 15) * 4;
    #pragma unroll
    for (int it = 0; it < 4; it++) {
        int k = rr + it * 16;
        float4 v = *(const float4*)(src + (size_t)(k0 + k) * 512 + n0 + c4);
        Ls[k][c4] = v.x; Ls[k][c4 + 1] = v.y; Ls[k][c4 + 2] = v.z; Ls[k][c4 + 3] = v.w;
    }
    __syncthreads();
    int n = tid >> 2, koff = (tid & 3) * 16;
    short8 o0, o1;
    #pragma unroll
    for (int j = 0; j < 8; j++) {
        o0[j] = (short)f2bf(Ls[koff + j][n]);
        o1[j] = (short)f2bf(Ls[koff + 8 + j][n]);
    }
    unsigned short* p = dst + (size_t)(n0 + n) * Kdim + k0 + koff;
    *(short8*)p = o0;
    *(short8*)(p + 8) = o1;
}

// ---------------------------------------------------------------------------
// K1: MFMA attention. Block = (head, q-quarter): 256 q rows, 4 waves x 4
// Q-tiles of 16. kv[1024][8] bf16 = Q=K=V tile; vt = V'^T with ones row at
// dim 8 (PV MFMA emits numerator AND softmax denominator in one C-frag).
// QK^T pads dk 8->32 with zeros (MFMA has ~70x headroom here).
// P round-trips LDS per-wave to convert C-layout -> A-layout (m120 pattern).
// ---------------------------------------------------------------------------
__global__ __launch_bounds__(256) void attn_mfma_kernel(const float* __restrict__ x,
                                                        const float* __restrict__ phi,
                                                        unsigned short* __restrict__ attn_bf) {
    int head = blockIdx.x >> 2;          // 0..255 = b*64+h
    int qquad = blockIdx.x & 3;
    int b = head >> 6, h = head & 63;

    __shared__ unsigned short kv[S * DK];        // [key][dk] bf16, 16 KB
    __shared__ unsigned short vt[16][S + 8];     // V'^T padded, 33 KB
    __shared__ unsigned short pbuf[4][16][40];   // per-wave P tile [q][key], 5 KB

    float ph[DK];
    #pragma unroll
    for (int d = 0; d < DK; d++) ph[d] = phi[d];

    int tid = threadIdx.x;
    for (int r = tid; r < S; r += 256) {
        const float* xp = x + ((size_t)(b * S + r)) * E + h * DK;
        float4 u = *(const float4*)xp;
        float4 v = *(const float4*)(xp + 4);
        float c[8];
        c[0] = cosf(u.x + ph[0]); c[1] = cosf(u.y + ph[1]);
        c[2] = cosf(u.z + ph[2]); c[3] = cosf(u.w + ph[3]);
        c[4] = cosf(v.x + ph[4]); c[5] = cosf(v.y + ph[5]);
        c[6] = cosf(v.z + ph[6]); c[7] = cosf(v.w + ph[7]);
        unsigned short cb[8];
        #pragma unroll
        for (int d = 0; d < DK; d++) cb[d] = f2bf(c[d]);
        unsigned* kp = (unsigned*)&kv[r * DK];
        #pragma unroll
        for (int d = 0; d < 4; d++)
            kp[d] = (unsigned)cb[2 * d] | ((unsigned)cb[2 * d + 1] << 16);
        #pragma unroll
        for (int d = 0; d < DK; d++) vt[d][r] = cb[d];
        vt[8][r] = 0x3F80;               // 1.0 bf16 (denominator row)
        #pragma unroll
        for (int d = 9; d < 16; d++) vt[d][r] = 0;
    }
    __syncthreads();

    int w = tid >> 6, lane = tid & 63;
    int col = lane & 15, g = lane >> 4;
    bool g0 = (g == 0);
    int q0 = qquad * 256 + w * 64;
    const float4a zc = {0.f, 0.f, 0.f, 0.f};

    for (int t = 0; t < 4; t++) {
        int m0 = q0 + t * 16;
        short8 aq = {0,0,0,0,0,0,0,0};   // A[m=col][k=g*8+j], dk valid only g==0
        if (g0) aq = *(const short8*)&kv[(m0 + col) * DK];

        float4a acc = {0.f, 0.f, 0.f, 0.f};
        for (int kb = 0; kb < S; kb += 32) {
            #pragma unroll
            for (int half = 0; half < 2; half++) {
                int n0 = kb + half * 16;
                short8 bk = {0,0,0,0,0,0,0,0};
                if (g0) bk = *(const short8*)&kv[(n0 + col) * DK];
                float4a s = __builtin_amdgcn_mfma_f32_16x16x32_bf16(aq, bk, zc, 0, 0, 0);
                // P = exp(s / sqrt(8)); C layout: row=g*4+r, col=key
                #pragma unroll
                for (int r2 = 0; r2 < 4; r2++) {
                    float p = __expf(s[r2] * 0.35355339059327373f);
                    pbuf[w][g * 4 + r2][half * 16 + col] = f2bf_trunc(p);
                }
            }
            __builtin_amdgcn_wave_barrier();   // keep LDS write->read ordered
            // PV: A[m=q col][k=key g*8+j] from pbuf, B[k=key][n=dim col] from vt
            short8 pf = *(const short8*)&pbuf[w][col][g * 8];
            short8 vf = *(const short8*)&vt[col][kb + g * 8];
            acc = __builtin_amdgcn_mfma_f32_16x16x32_bf16(pf, vf, acc, 0, 0, 0);
            __builtin_amdgcn_wave_barrier();   // next iter overwrites pbuf
        }
        // acc: O'[q=m0+g*4+r][dim=col]; denom at dim 8 of same row
        #pragma unroll
        for (int r2 = 0; r2 < 4; r2++) {
            float denom = __shfl(acc[r2], (lane & 48) | 8);
            if (col < DK) {
                size_t o = ((size_t)(b * S + m0 + g * 4 + r2)) * E + h * DK + col;
                attn_bf[o] = f2bf(acc[r2] / denom);
            }
        }
    }
}

// ---------------------------------------------------------------------------
// K2: combine-heads GEMM via MFMA, no LDS, no barriers.
// ---------------------------------------------------------------------------
__global__ __launch_bounds__(256) void combine_mfma(const unsigned short* __restrict__ A,
                                                    const unsigned short* __restrict__ Bt,
                                                    const float* __restrict__ bias,
                                                    unsigned short* __restrict__ Cbf) {
    int tid = threadIdx.x;
    int w = tid >> 6, lane = tid & 63;
    int row = lane & 15, g = lane >> 4, g8 = g * 8;
    int m0 = blockIdx.x * 64, n0 = blockIdx.y * 128;
    int mbase = m0 + w * 16;

    float4a acc[8];
    #pragma unroll
    for (int nt = 0; nt < 8; nt++) acc[nt] = 0.f;

    const unsigned short* ap = A + (size_t)(mbase + row) * 512 + g8;
    for (int kb = 0; kb < 512; kb += 32) {
        short8 af = *(const short8*)(ap + kb);
        #pragma unroll
        for (int nt = 0; nt < 8; nt++) {
            short8 bf = *(const short8*)(Bt + (size_t)(n0 + nt * 16 + row) * 512 + kb + g8);
            acc[nt] = __builtin_amdgcn_mfma_f32_16x16x32_bf16(af, bf, acc[nt], 0, 0, 0);
        }
    }
    int crow = mbase + g * 4;
    #pragma unroll
    for (int nt = 0; nt < 8; nt++) {
        int col = n0 + nt * 16 + row;
        float bb = bias[col];
        #pragma unroll
        for (int r = 0; r < 4; r++)
            Cbf[(size_t)(crow + r) * 512 + col] = f2bf(acc[nt][r] + bb);
    }
}

// ---------------------------------------------------------------------------
// K4: FFN via MFMA: C = relu(qout@W1+b1) @ W2 + b2. h computed per-lane in
// registers directly in A-frag layout from LDS-resident W1.
// ---------------------------------------------------------------------------
__global__ __launch_bounds__(256) void ffn_mfma(const float* __restrict__ qout,
                                                const float* __restrict__ W1,
                                                const float* __restrict__ b1,
                                                const unsigned short* __restrict__ W2t,
                                                const float* __restrict__ b2,
                                                unsigned short* __restrict__ Cbf) {
    __shared__ float w1s[8 * FFN];       // 64 KB
    __shared__ float b1s[FFN];           // 8 KB
    __shared__ float qs[64 * DK];        // 2 KB
    int tid = threadIdx.x;
    {
        const float4* s = (const float4*)W1; float4* d = (float4*)w1s;
        for (int i = tid; i < 8 * FFN / 4; i += 256) d[i] = s[i];
        const float4* sb = (const float4*)b1; float4* db = (float4*)b1s;
        for (int i = tid; i < FFN / 4; i += 256) db[i] = sb[i];
    }
    int m0 = blockIdx.x * 64, n0 = blockIdx.y * 128;
    if (tid < 128) ((float4*)qs)[tid] = ((const float4*)(qout + (size_t)m0 * DK))[tid];
    __syncthreads();

    int w = tid >> 6, lane = tid & 63;
    int row = lane & 15, g = lane >> 4, g8 = g * 8;
    float qv[8];
    #pragma unroll
    for (int i = 0; i < 8; i++) qv[i] = qs[(w * 16 + row) * 8 + i];

    float4a acc[8];
    #pragma unroll
    for (int nt = 0; nt < 8; nt++) acc[nt] = 0.f;

    for (int kb = 0; kb < FFN; kb += 32) {
        float hv[8];
        const float* bp = &b1s[kb + g8];
        #pragma unroll
        for (int j = 0; j < 8; j++) hv[j] = bp[j];
        #pragma unroll
        for (int i = 0; i < 8; i++) {
            const float* wp = &w1s[i * FFN + kb + g8];
            float qi = qv[i];
            #pragma unroll
            for (int j = 0; j < 8; j++) hv[j] = fmaf(qi, wp[j], hv[j]);
        }
        short8 af;
        #pragma unroll
        for (int j = 0; j < 8; j++) af[j] = (short)f2bf(fmaxf(hv[j], 0.f));
        #pragma unroll
        for (int nt = 0; nt < 8; nt++) {
            short8 bf = *(const short8*)(W2t + (size_t)(n0 + nt * 16 + row) * FFN + kb + g8);
            acc[nt] = __builtin_amdgcn_mfma_f32_16x16x32_bf16(af, bf, acc[nt], 0, 0, 0);
        }
    }
    int crow = m0 + w * 16 + g * 4;
    #pragma unroll
    for (int nt = 0; nt < 8; nt++) {
        int col = n0 + nt * 16 + row;
        float bb = b2[col];
        #pragma unroll
        for (int r = 0; r < 4; r++)
            Cbf[(size_t)(crow + r) * 512 + col] = f2bf(acc[nt][r] + bb);
    }
}

// ---------------------------------------------------------------------------
// K3/K5: LayerNorm over E=512, residual bf16, float2-vectorized.
// Optional epilogue: qout[t,i] = cos(out[t,i]) * cos(theta[i]) for i<8.
// ---------------------------------------------------------------------------
__global__ __launch_bounds__(256) void ln_kernel(const float* a,
                                                 const unsigned short* __restrict__ r,
                                                 const float* __restrict__ g,
                                                 const float* __restrict__ be,
                                                 float* out,
                                                 float* __restrict__ qout,
                                                 const float* __restrict__ theta) {
    int t = blockIdx.x, tid = threadIdx.x;
    size_t base = (size_t)t * E;
    int e0 = tid * 2;
    float2 av = *(const float2*)&a[base + e0];
    unsigned rv = *(const unsigned*)&r[base + e0];
    float v0 = av.x + bf2f((unsigned short)(rv & 0xffff));
    float v1 = av.y + bf2f((unsigned short)(rv >> 16));
    float s  = v0 + v1;
    float sq = v0 * v0 + v1 * v1;
    #pragma unroll
    for (int off = 32; off > 0; off >>= 1) {
        s  += __shfl_down(s, off);
        sq += __shfl_down(sq, off);
    }
    __shared__ float ls[4], lq[4];
    int wave = tid >> 6, lane = tid & 63;
    if (lane == 0) { ls[wave] = s; lq[wave] = sq; }
    __syncthreads();
    if (tid == 0) {
        float SS = ls[0] + ls[1] + ls[2] + ls[3];
        float QQ = lq[0] + lq[1] + lq[2] + lq[3];
        float mu = SS * (1.f / E);
        float var = QQ * (1.f / E) - mu * mu;
        ls[0] = mu;
        lq[0] = rsqrtf(var + 1e-5f);
    }
    __syncthreads();
    float mu = ls[0], rstd = lq[0];
    float2 gv = *(const float2*)&g[e0];
    float2 bv = *(const float2*)&be[e0];
    float y0 = (v0 - mu) * rstd * gv.x + bv.x;
    float y1 = (v1 - mu) * rstd * gv.y + bv.y;
    *(float2*)&out[base + e0] = make_float2(y0, y1);
    if (qout != nullptr && tid < 4) {
        qout[t * DK + e0]     = cosf(y0) * cosf(theta[e0]);
        qout[t * DK + e0 + 1] = cosf(y1) * cosf(theta[e0 + 1]);
    }
}

// ---------------------------------------------------------------------------
// launch — ws: proj_bf 4MB + Wct 0.5MB + W2t 2MB + qout 128KB = 6.63 MB.
// d_out doubles as scratch: attn_bf (4MB bf16), then x1 (8MB fp32), LN2 in-place.
// ---------------------------------------------------------------------------
extern "C" void kernel_launch(void* const* d_in, const int* in_sizes, int n_in,
                              void* d_out, int out_size, void* d_ws, size_t ws_size,
                              hipStream_t stream) {
    const float* x     = (const float*)d_in[0];
    const float* phi   = (const float*)d_in[1];
    const float* Wc    = (const float*)d_in[2];
    const float* bc    = (const float*)d_in[3];
    const float* theta = (const float*)d_in[4];
    const float* W1    = (const float*)d_in[5];
    const float* b1    = (const float*)d_in[6];
    const float* W2    = (const float*)d_in[7];
    const float* b2    = (const float*)d_in[8];
    const float* g1    = (const float*)d_in[9];
    const float* be1   = (const float*)d_in[10];
    const float* g2    = (const float*)d_in[11];
    const float* be2   = (const float*)d_in[12];
    float* out = (float*)d_out;

    float* ws = (float*)d_ws;
    unsigned short* proj_bf = (unsigned short*)ws;                       // [4096][512] bf16
    unsigned short* Wct     = (unsigned short*)(ws + 1048576);           // [512][512] bf16
    unsigned short* W2t     = (unsigned short*)(ws + 1048576 + 131072);  // [512][2048] bf16
    float*          qout    = ws + 1048576 + 131072 + 524288;            // [4096][8] fp32
    unsigned short* attn_bf = (unsigned short*)d_out;                    // [4096][512] bf16

    convert_kernel<<<320, 256, 0, stream>>>(Wc, W2, Wct, W2t);
    attn_mfma_kernel<<<B * H * 4, 256, 0, stream>>>(x, phi, attn_bf);
    combine_mfma<<<dim3(64, 4), 256, 0, stream>>>(attn_bf, Wct, bc, proj_bf);
    ln_kernel<<<BS, 256, 0, stream>>>(x, proj_bf, g1, be1, out, qout, theta);
    ffn_mfma<<<dim3(64, 4), 256, 0, stream>>>(qout, W1, b1, W2t, b2, proj_bf);
    ln_kernel<<<BS, 256, 0, stream>>>(out, proj_bf, g2, be2, out, nullptr, nullptr);
}

// Round 5
// 249.688 us; speedup vs baseline: 1.8518x; 1.1656x over previous
//
#include <hip/hip_runtime.h>
#include <hip/hip_bf16.h>
#include <math.h>

// Problem dims (fixed)
#define B 4
#define S 1024
#define E 512
#define H 64
#define DK 8
#define FFN 2048
#define BS (B*S)          // 4096 tokens

typedef __attribute__((ext_vector_type(8))) short short8;   // 8 bf16 (4 VGPRs)
typedef __attribute__((ext_vector_type(4))) float float4a;  // MFMA C/D frag

union U8 { short8 v; unsigned u[4]; };
union F4 { float4a v; float f[4]; };

// fp32 -> bf16 round-to-nearest-even
__device__ __forceinline__ unsigned short f2bf(float f) {
    unsigned u = __builtin_bit_cast(unsigned, f);
    u = (u + 0x7fffu + ((u >> 16) & 1u)) >> 16;
    return (unsigned short)u;
}
__device__ __forceinline__ float bf2f(unsigned short h) {
    return __builtin_bit_cast(float, (unsigned)h << 16);
}
// one-op pack: (trunc_bf16(a) << 16) | trunc_bf16(b)
__device__ __forceinline__ unsigned packbf(float a, float b) {
    return __builtin_amdgcn_perm(__builtin_bit_cast(unsigned, a),
                                 __builtin_bit_cast(unsigned, b), 0x07060302u);
}
// rounded pack: (rn_bf16(a) << 16) | rn_bf16(b)
__device__ __forceinline__ unsigned packbf_rn(float a, float b) {
    return ((unsigned)f2bf(a) << 16) | f2bf(b);
}
// key/f permutation within 32-blocks: frag position g*8+4h+r <-> index 16h+4g+r
__device__ __forceinline__ int pidx(int k) {
    return (k & ~31) | (((k >> 2) & 3) << 3) | (((k >> 4) & 1) << 2) | (k & 3);
}

// ---------------------------------------------------------------------------
// K0: weight conversion.
//  bid 0..63   : Wc[512][512] fp32 -> Wct[n][k] bf16 (plain transpose)
//  bid 64..319 : W2[2048][512] fp32 -> W2tp[n][pidx(k)] bf16 (pi-permuted k)
//  bid 320     : W1[8][2048] fp32 -> W1t[f][i] bf16 (transpose, i-contig)
// ---------------------------------------------------------------------------
__global__ __launch_bounds__(256) void convert_kernel(const float* __restrict__ Wc,
                                                      const float* __restrict__ W2,
                                                      const float* __restrict__ W1,
                                                      unsigned short* __restrict__ Wct,
                                                      unsigned short* __restrict__ W2tp,
                                                      unsigned short* __restrict__ W1t) {
    int bid = blockIdx.x;
    int tid = threadIdx.x;
    if (bid == 320) {                    // W1 transpose
        int f0 = tid * 8;
        float vals[8][8];                // [i][jf]
        #pragma unroll
        for (int i = 0; i < 8; i++) {
            float4 a = *(const float4*)&W1[i * FFN + f0];
            float4 c = *(const float4*)&W1[i * FFN + f0 + 4];
            vals[i][0]=a.x; vals[i][1]=a.y; vals[i][2]=a.z; vals[i][3]=a.w;
            vals[i][4]=c.x; vals[i][5]=c.y; vals[i][6]=c.z; vals[i][7]=c.w;
        }
        #pragma unroll
        for (int jf = 0; jf < 8; jf++) {
            U8 o;
            o.u[0] = packbf_rn(vals[1][jf], vals[0][jf]);
            o.u[1] = packbf_rn(vals[3][jf], vals[2][jf]);
            o.u[2] = packbf_rn(vals[5][jf], vals[4][jf]);
            o.u[3] = packbf_rn(vals[7][jf], vals[6][jf]);
            *(short8*)&W1t[(f0 + jf) * DK] = o.v;
        }
        return;
    }
    const float* src; int Kdim, kt, nt; bool permute;
    if (bid < 64) { src = Wc; Kdim = 512;  kt = bid >> 3;        nt = bid & 7; permute = false; }
    else          { src = W2; Kdim = 2048; kt = (bid - 64) >> 3; nt = (bid - 64) & 7; permute = true; }
    int k0 = kt * 64, n0 = nt * 64;
    __shared__ float Ls[64][65];
    int rr = tid >> 4, c4 = (tid & 15) * 4;
    #pragma unroll
    for (int it = 0; it < 4; it++) {
        int k = rr + it * 16;
        float4 v = *(const float4*)(src + (size_t)(k0 + k) * 512 + n0 + c4);
        Ls[k][c4] = v.x; Ls[k][c4 + 1] = v.y; Ls[k][c4 + 2] = v.z; Ls[k][c4 + 3] = v.w;
    }
    __syncthreads();
    int n = tid >> 2, koff = (tid & 3) * 16;
    if (!permute) {
        short8 o0, o1;
        #pragma unroll
        for (int j = 0; j < 8; j++) {
            o0[j] = (short)f2bf(Ls[koff + j][n]);
            o1[j] = (short)f2bf(Ls[koff + 8 + j][n]);
        }
        unsigned short* p = Wct + (size_t)(n0 + n) * Kdim + k0 + koff;
        *(short8*)p = o0;
        *(short8*)(p + 8) = o1;
    } else {
        float v[16];
        #pragma unroll
        for (int m = 0; m < 16; m++) v[m] = Ls[koff + m][n];
        int h = (koff >> 4) & 1;
        int base32 = koff & ~31;
        unsigned short* p = W2tp + (size_t)(n0 + n) * Kdim + k0 + base32 + 4 * h;
        #pragma unroll
        for (int g2 = 0; g2 < 4; g2++) {
            uint2 o;
            o.x = packbf_rn(v[4*g2+1], v[4*g2+0]);
            o.y = packbf_rn(v[4*g2+3], v[4*g2+2]);
            *(uint2*)(p + 8 * g2) = o;       // dst u16 idx: base32 + 8*g2 + 4*h + r
        }
    }
}

// ---------------------------------------------------------------------------
// K1: MFMA attention, transpose-free via key permutation.
// S^T = mfma(A=K, B=Q): lane (g,col) holds p(key=kb+16h+4g+r, q=col).
// V stored permuted (vtp[d][pidx(key)]) so the PV B-frag (P^T) is a
// lane-LOCAL repack (4 v_perm) and O^T = mfma(A=V'^T, B=P^T, acc).
// Ones-row at dim 8 gives the softmax denominator in the same C-frag.
// ---------------------------------------------------------------------------
__global__ __launch_bounds__(256) void attn_mfma_kernel(const float* __restrict__ x,
                                                        const float* __restrict__ phi,
                                                        unsigned short* __restrict__ attn_bf) {
    int head = blockIdx.x >> 2, qquad = blockIdx.x & 3;
    int b = head >> 6, hh = head & 63;

    __shared__ unsigned short kv[S * DK];       // 16 KB  [key][dk]
    __shared__ unsigned short vtp[9][S + 8];    // 18.6 KB [dim0..7 + ones][perm key]

    float ph[DK];
    #pragma unroll
    for (int d = 0; d < DK; d++) ph[d] = phi[d];

    int tid = threadIdx.x;
    for (int r = tid; r < S; r += 256) {
        const float* xp = x + ((size_t)(b * S + r)) * E + hh * DK;
        float4 u = *(const float4*)xp;
        float4 v = *(const float4*)(xp + 4);
        float c[8] = {cosf(u.x+ph[0]), cosf(u.y+ph[1]), cosf(u.z+ph[2]), cosf(u.w+ph[3]),
                      cosf(v.x+ph[4]), cosf(v.y+ph[5]), cosf(v.z+ph[6]), cosf(v.w+ph[7])};
        unsigned short cb[8];
        #pragma unroll
        for (int d = 0; d < DK; d++) cb[d] = f2bf(c[d]);
        unsigned* kp = (unsigned*)&kv[r * DK];
        #pragma unroll
        for (int d = 0; d < 4; d++)
            kp[d] = (unsigned)cb[2*d] | ((unsigned)cb[2*d+1] << 16);
        int pr = pidx(r);
        #pragma unroll
        for (int d = 0; d < DK; d++) vtp[d][pr] = cb[d];
        vtp[8][pr] = 0x3F80;                // 1.0 bf16 (denominator row)
    }
    __syncthreads();

    int w = tid >> 6, lane = tid & 63, col = lane & 15, g = lane >> 4;
    bool g0 = (g == 0);
    int q0 = qquad * 256 + w * 64;
    const short8 z8 = {0,0,0,0,0,0,0,0};
    const float4a zc = {0.f,0.f,0.f,0.f};

    short8 aq[4];                            // Q B-frags, 4 q-tiles of 16
    #pragma unroll
    for (int t = 0; t < 4; t++)
        aq[t] = g0 ? *(const short8*)&kv[(q0 + t*16 + col) * DK] : z8;

    float4a acc[4];
    #pragma unroll
    for (int t = 0; t < 4; t++) acc[t] = zc;

    int vrow = col < 8 ? col : 8;            // clamp: dims 9..15 get denom dups
    const unsigned short* vbase = &vtp[vrow][0];

    for (int kb = 0; kb < S; kb += 32) {
        short8 bk0 = g0 ? *(const short8*)&kv[(kb + col) * DK] : z8;
        short8 bk1 = g0 ? *(const short8*)&kv[(kb + 16 + col) * DK] : z8;
        short8 vf = *(const short8*)(vbase + kb + g * 8);
        #pragma unroll
        for (int t = 0; t < 4; t++) {
            float4a s0 = __builtin_amdgcn_mfma_f32_16x16x32_bf16(bk0, aq[t], zc, 0,0,0);
            float4a s1 = __builtin_amdgcn_mfma_f32_16x16x32_bf16(bk1, aq[t], zc, 0,0,0);
            F4 S0, S1; S0.v = s0; S1.v = s1;
            float e00 = __expf(S0.f[0] * 0.35355339f);
            float e01 = __expf(S0.f[1] * 0.35355339f);
            float e02 = __expf(S0.f[2] * 0.35355339f);
            float e03 = __expf(S0.f[3] * 0.35355339f);
            float e10 = __expf(S1.f[0] * 0.35355339f);
            float e11 = __expf(S1.f[1] * 0.35355339f);
            float e12 = __expf(S1.f[2] * 0.35355339f);
            float e13 = __expf(S1.f[3] * 0.35355339f);
            U8 pf;                           // lane-local P^T B-frag (pi-ordered keys)
            pf.u[0] = packbf(e01, e00);
            pf.u[1] = packbf(e03, e02);
            pf.u[2] = packbf(e11, e10);
            pf.u[3] = packbf(e13, e12);
            acc[t] = __builtin_amdgcn_mfma_f32_16x16x32_bf16(vf, pf.v, acc[t], 0,0,0);
        }
    }
    // acc[t]: O'[dim=4g+r][q=col]; denom = dim 8 = lane 32+col, reg 0
    #pragma unroll
    for (int t = 0; t < 4; t++) {
        F4 a; a.v = acc[t];
        float denom = __shfl(a.f[0], 32 + col);
        float inv = __builtin_amdgcn_rcpf(denom);
        if (g < 2) {
            int token = b * S + q0 + t * 16 + col;
            uint2 o;
            o.x = packbf_rn(a.f[1] * inv, a.f[0] * inv);
            o.y = packbf_rn(a.f[3] * inv, a.f[2] * inv);
            *(uint2*)&attn_bf[(size_t)token * E + hh * DK + g * 4] = o;
        }
    }
}

// ---------------------------------------------------------------------------
// K2: combine-heads GEMM via MFMA, no LDS, no barriers. (unchanged, validated)
// ---------------------------------------------------------------------------
__global__ __launch_bounds__(256) void combine_mfma(const unsigned short* __restrict__ A,
                                                    const unsigned short* __restrict__ Bt,
                                                    const float* __restrict__ bias,
                                                    unsigned short* __restrict__ Cbf) {
    int tid = threadIdx.x;
    int w = tid >> 6, lane = tid & 63;
    int row = lane & 15, g = lane >> 4, g8 = g * 8;
    int m0 = blockIdx.x * 64, n0 = blockIdx.y * 128;
    int mbase = m0 + w * 16;

    float4a acc[8];
    #pragma unroll
    for (int nt = 0; nt < 8; nt++) acc[nt] = 0.f;

    const unsigned short* ap = A + (size_t)(mbase + row) * 512 + g8;
    for (int kb = 0; kb < 512; kb += 32) {
        short8 af = *(const short8*)(ap + kb);
        #pragma unroll
        for (int nt = 0; nt < 8; nt++) {
            short8 bf = *(const short8*)(Bt + (size_t)(n0 + nt * 16 + row) * 512 + kb + g8);
            acc[nt] = __builtin_amdgcn_mfma_f32_16x16x32_bf16(af, bf, acc[nt], 0, 0, 0);
        }
    }
    int crow = mbase + g * 4;
    #pragma unroll
    for (int nt = 0; nt < 8; nt++) {
        int col = n0 + nt * 16 + row;
        float bb = bias[col];
        #pragma unroll
        for (int r = 0; r < 4; r++)
            Cbf[(size_t)(crow + r) * 512 + col] = f2bf(acc[nt][r] + bb);
    }
}

// ---------------------------------------------------------------------------
// K4: FFN, transpose-free via the same pi trick.
// H^T = mfma(A=W1^T-frag, B=qout-frag) -> bias+relu -> lane-local pack
// (f-axis pi-permuted) -> OUT^T = mfma(A=W2tp-frag, B=H^T, acc).
// Block = 64 tokens x 64 n; wave = 16-token tile x 4 n-tiles.
// ---------------------------------------------------------------------------
__global__ __launch_bounds__(256) void ffn_mfma(const unsigned short* __restrict__ qbf,
                                                const unsigned short* __restrict__ W1tg,
                                                const float* __restrict__ b1,
                                                const unsigned short* __restrict__ W2tp,
                                                const float* __restrict__ b2,
                                                unsigned short* __restrict__ Cbf) {
    __shared__ unsigned short w1t[FFN * DK];   // 32 KB [f][i]
    __shared__ float b1s[FFN];                 // 8 KB
    int tid = threadIdx.x;
    for (int i = tid; i < FFN * DK / 8; i += 256)
        ((uint4*)w1t)[i] = ((const uint4*)W1tg)[i];
    for (int i = tid; i < FFN / 4; i += 256)
        ((float4*)b1s)[i] = ((const float4*)b1)[i];
    __syncthreads();

    int w = tid >> 6, lane = tid & 63, col = lane & 15, g = lane >> 4;
    bool g0 = (g == 0);
    int m0 = blockIdx.x * 64, n0 = blockIdx.y * 64;
    int mw = m0 + w * 16;
    const short8 z8 = {0,0,0,0,0,0,0,0};
    const float4a zc = {0.f,0.f,0.f,0.f};

    short8 qf = g0 ? *(const short8*)&qbf[(mw + col) * DK] : z8;

    float4a acc[4];
    #pragma unroll
    for (int nt = 0; nt < 4; nt++) acc[nt] = zc;
    float4 b2v[4];
    #pragma unroll
    for (int nt = 0; nt < 4; nt++) b2v[nt] = *(const float4*)&b2[n0 + nt*16 + 4*g];

    for (int kb = 0; kb < FFN; kb += 32) {
        short8 w1f0 = g0 ? *(const short8*)&w1t[(kb + col) * DK] : z8;
        short8 w1f1 = g0 ? *(const short8*)&w1t[(kb + 16 + col) * DK] : z8;
        float4a h0 = __builtin_amdgcn_mfma_f32_16x16x32_bf16(w1f0, qf, zc, 0,0,0);
        float4a h1 = __builtin_amdgcn_mfma_f32_16x16x32_bf16(w1f1, qf, zc, 0,0,0);
        float4 bb0 = *(const float4*)&b1s[kb + 4*g];          // f = kb+4g+r
        float4 bb1 = *(const float4*)&b1s[kb + 16 + 4*g];     // f = kb+16+4g+r
        F4 H0, H1; H0.v = h0; H1.v = h1;
        float e00 = fmaxf(H0.f[0] + bb0.x, 0.f);
        float e01 = fmaxf(H0.f[1] + bb0.y, 0.f);
        float e02 = fmaxf(H0.f[2] + bb0.z, 0.f);
        float e03 = fmaxf(H0.f[3] + bb0.w, 0.f);
        float e10 = fmaxf(H1.f[0] + bb1.x, 0.f);
        float e11 = fmaxf(H1.f[1] + bb1.y, 0.f);
        float e12 = fmaxf(H1.f[2] + bb1.z, 0.f);
        float e13 = fmaxf(H1.f[3] + bb1.w, 0.f);
        U8 pf;                               // H^T B-frag, pi-ordered f
        pf.u[0] = packbf(e01, e00);
        pf.u[1] = packbf(e03, e02);
        pf.u[2] = packbf(e11, e10);
        pf.u[3] = packbf(e13, e12);
        #pragma unroll
        for (int nt = 0; nt < 4; nt++) {
            short8 af = *(const short8*)&W2tp[(size_t)(n0 + nt*16 + col) * FFN + kb + g*8];
            acc[nt] = __builtin_amdgcn_mfma_f32_16x16x32_bf16(af, pf.v, acc[nt], 0,0,0);
        }
    }
    // acc[nt]: OUT^T[n_local=4g+r][token=col]
    #pragma unroll
    for (int nt = 0; nt < 4; nt++) {
        F4 a; a.v = acc[nt];
        float4 bb = b2v[nt];
        uint2 o;
        o.x = packbf_rn(a.f[1] + bb.y, a.f[0] + bb.x);
        o.y = packbf_rn(a.f[3] + bb.w, a.f[2] + bb.z);
        *(uint2*)&Cbf[(size_t)(mw + col) * E + n0 + nt * 16 + 4 * g] = o;
    }
}

// ---------------------------------------------------------------------------
// K3/K5: LayerNorm over E=512, residual bf16, float2-vectorized.
// Optional epilogue: qoutbf[t][i] = bf16(cos(y_i) * cos(theta_i)), i<8.
// ---------------------------------------------------------------------------
__global__ __launch_bounds__(256) void ln_kernel(const float* a,
                                                 const unsigned short* __restrict__ r,
                                                 const float* __restrict__ g,
                                                 const float* __restrict__ be,
                                                 float* out,
                                                 unsigned short* __restrict__ qoutbf,
                                                 const float* __restrict__ theta) {
    int t = blockIdx.x, tid = threadIdx.x;
    size_t base = (size_t)t * E;
    int e0 = tid * 2;
    float2 av = *(const float2*)&a[base + e0];
    unsigned rv = *(const unsigned*)&r[base + e0];
    float v0 = av.x + bf2f((unsigned short)(rv & 0xffff));
    float v1 = av.y + bf2f((unsigned short)(rv >> 16));
    float s  = v0 + v1;
    float sq = v0 * v0 + v1 * v1;
    #pragma unroll
    for (int off = 32; off > 0; off >>= 1) {
        s  += __shfl_down(s, off);
        sq += __shfl_down(sq, off);
    }
    __shared__ float ls[4], lq[4];
    int wave = tid >> 6, lane = tid & 63;
    if (lane == 0) { ls[wave] = s; lq[wave] = sq; }
    __syncthreads();
    if (tid == 0) {
        float SS = ls[0] + ls[1] + ls[2] + ls[3];
        float QQ = lq[0] + lq[1] + lq[2] + lq[3];
        float mu = SS * (1.f / E);
        float var = QQ * (1.f / E) - mu * mu;
        ls[0] = mu;
        lq[0] = rsqrtf(var + 1e-5f);
    }
    __syncthreads();
    float mu = ls[0], rstd = lq[0];
    float2 gv = *(const float2*)&g[e0];
    float2 bv = *(const float2*)&be[e0];
    float y0 = (v0 - mu) * rstd * gv.x + bv.x;
    float y1 = (v1 - mu) * rstd * gv.y + bv.y;
    *(float2*)&out[base + e0] = make_float2(y0, y1);
    if (qoutbf != nullptr && tid < 4) {
        float q0v = cosf(y0) * cosf(theta[e0]);
        float q1v = cosf(y1) * cosf(theta[e0 + 1]);
        *(unsigned*)&qoutbf[t * DK + e0] = packbf_rn(q1v, q0v);
    }
}

// ---------------------------------------------------------------------------
// launch — ws: proj_bf 4MB + Wct 0.5MB + W2tp 2MB + W1t 32KB + qoutbf 64KB
// = 6.59 MB (under the 8.13 MB proven-safe budget). d_out doubles as scratch:
// attn_bf (4MB bf16), then x1 (8MB fp32), LN2 in-place.
// ---------------------------------------------------------------------------
extern "C" void kernel_launch(void* const* d_in, const int* in_sizes, int n_in,
                              void* d_out, int out_size, void* d_ws, size_t ws_size,
                              hipStream_t stream) {
    const float* x     = (const float*)d_in[0];
    const float* phi   = (const float*)d_in[1];
    const float* Wc    = (const float*)d_in[2];
    const float* bc    = (const float*)d_in[3];
    const float* theta = (const float*)d_in[4];
    const float* W1    = (const float*)d_in[5];
    const float* b1    = (const float*)d_in[6];
    const float* W2    = (const float*)d_in[7];
    const float* b2    = (const float*)d_in[8];
    const float* g1    = (const float*)d_in[9];
    const float* be1   = (const float*)d_in[10];
    const float* g2    = (const float*)d_in[11];
    const float* be2   = (const float*)d_in[12];
    float* out = (float*)d_out;

    float* ws = (float*)d_ws;
    unsigned short* proj_bf = (unsigned short*)ws;                                // 4 MB
    unsigned short* Wct     = (unsigned short*)(ws + 1048576);                    // 0.5 MB
    unsigned short* W2tp    = (unsigned short*)(ws + 1048576 + 131072);           // 2 MB
    unsigned short* W1t     = (unsigned short*)(ws + 1048576 + 131072 + 524288);  // 32 KB
    unsigned short* qoutbf  = (unsigned short*)(ws + 1048576 + 131072 + 524288 + 8192); // 64 KB
    unsigned short* attn_bf = (unsigned short*)d_out;

    convert_kernel<<<321, 256, 0, stream>>>(Wc, W2, W1, Wct, W2tp, W1t);
    attn_mfma_kernel<<<B * H * 4, 256, 0, stream>>>(x, phi, attn_bf);
    combine_mfma<<<dim3(64, 4), 256, 0, stream>>>(attn_bf, Wct, bc, proj_bf);
    ln_kernel<<<BS, 256, 0, stream>>>(x, proj_bf, g1, be1, out, qoutbf, theta);
    ffn_mfma<<<dim3(64, 8), 256, 0, stream>>>(qoutbf, W1t, b1, W2tp, b2, proj_bf);
    ln_kernel<<<BS, 256, 0, stream>>>(out, proj_bf, g2, be2, out, nullptr, nullptr);
}

// Round 6
// 231.589 us; speedup vs baseline: 1.9965x; 1.0782x over previous
//
#include <hip/hip_runtime.h>
#include <hip/hip_bf16.h>
#include <math.h>

// Problem dims (fixed)
#define B 4
#define S 1024
#define E 512
#define H 64
#define DK 8
#define FFN 2048
#define BS (B*S)          // 4096 tokens

// kv pre-scale: CSCALE^2 = (1/sqrt(8)) * log2(e) so exp(score/sqrt(8)) = 2^(scaled score)
#define CSCALE 0.7141879f

#if __has_builtin(__builtin_amdgcn_exp2f)
#define EXP2F(x) __builtin_amdgcn_exp2f(x)
#else
#define EXP2F(x) exp2f(x)
#endif

typedef __attribute__((ext_vector_type(8))) short short8;   // 8 bf16 (4 VGPRs)
typedef __attribute__((ext_vector_type(4))) float float4a;  // MFMA C/D frag

union U8 { short8 v; unsigned u[4]; };
union F4 { float4a v; float f[4]; };

// fp32 -> bf16 round-to-nearest-even
__device__ __forceinline__ unsigned short f2bf(float f) {
    unsigned u = __builtin_bit_cast(unsigned, f);
    u = (u + 0x7fffu + ((u >> 16) & 1u)) >> 16;
    return (unsigned short)u;
}
__device__ __forceinline__ float bf2f(unsigned short h) {
    return __builtin_bit_cast(float, (unsigned)h << 16);
}
// one-op pack: (trunc_bf16(a) << 16) | trunc_bf16(b)
__device__ __forceinline__ unsigned packbf(float a, float b) {
    return __builtin_amdgcn_perm(__builtin_bit_cast(unsigned, a),
                                 __builtin_bit_cast(unsigned, b), 0x07060302u);
}
// rounded pack: (rn_bf16(a) << 16) | rn_bf16(b)
__device__ __forceinline__ unsigned packbf_rn(float a, float b) {
    return ((unsigned)f2bf(a) << 16) | f2bf(b);
}
// key/f permutation within 32-blocks: frag position g*8+4h+r <-> index 16h+4g+r
__device__ __forceinline__ int pidx(int k) {
    return (k & ~31) | (((k >> 2) & 3) << 3) | (((k >> 4) & 1) << 2) | (k & 3);
}

// ---------------------------------------------------------------------------
// K0: weight conversion.
//  bid 0..63   : Wc[512][512] fp32 -> Wct[n][k] bf16 (plain transpose)
//  bid 64..319 : W2[2048][512] fp32 -> W2tp[n][pidx(k)] bf16 (pi-permuted k)
//  bid 320     : W1[8][2048] fp32 -> W1t[f][i] bf16 (transpose, i-contig)
// ---------------------------------------------------------------------------
__global__ __launch_bounds__(256) void convert_kernel(const float* __restrict__ Wc,
                                                      const float* __restrict__ W2,
                                                      const float* __restrict__ W1,
                                                      unsigned short* __restrict__ Wct,
                                                      unsigned short* __restrict__ W2tp,
                                                      unsigned short* __restrict__ W1t) {
    int bid = blockIdx.x;
    int tid = threadIdx.x;
    if (bid == 320) {                    // W1 transpose
        int f0 = tid * 8;
        float vals[8][8];                // [i][jf]
        #pragma unroll
        for (int i = 0; i < 8; i++) {
            float4 a = *(const float4*)&W1[i * FFN + f0];
            float4 c = *(const float4*)&W1[i * FFN + f0 + 4];
            vals[i][0]=a.x; vals[i][1]=a.y; vals[i][2]=a.z; vals[i][3]=a.w;
            vals[i][4]=c.x; vals[i][5]=c.y; vals[i][6]=c.z; vals[i][7]=c.w;
        }
        #pragma unroll
        for (int jf = 0; jf < 8; jf++) {
            U8 o;
            o.u[0] = packbf_rn(vals[1][jf], vals[0][jf]);
            o.u[1] = packbf_rn(vals[3][jf], vals[2][jf]);
            o.u[2] = packbf_rn(vals[5][jf], vals[4][jf]);
            o.u[3] = packbf_rn(vals[7][jf], vals[6][jf]);
            *(short8*)&W1t[(f0 + jf) * DK] = o.v;
        }
        return;
    }
    const float* src; int Kdim, kt, nt; bool permute;
    if (bid < 64) { src = Wc; Kdim = 512;  kt = bid >> 3;        nt = bid & 7; permute = false; }
    else          { src = W2; Kdim = 2048; kt = (bid - 64) >> 3; nt = (bid - 64) & 7; permute = true; }
    int k0 = kt * 64, n0 = nt * 64;
    __shared__ float Ls[64][65];
    int rr = tid >> 4, c4 = (tid & 15) * 4;
    #pragma unroll
    for (int it = 0; it < 4; it++) {
        int k = rr + it * 16;
        float4 v = *(const float4*)(src + (size_t)(k0 + k) * 512 + n0 + c4);
        Ls[k][c4] = v.x; Ls[k][c4 + 1] = v.y; Ls[k][c4 + 2] = v.z; Ls[k][c4 + 3] = v.w;
    }
    __syncthreads();
    int n = tid >> 2, koff = (tid & 3) * 16;
    if (!permute) {
        short8 o0, o1;
        #pragma unroll
        for (int j = 0; j < 8; j++) {
            o0[j] = (short)f2bf(Ls[koff + j][n]);
            o1[j] = (short)f2bf(Ls[koff + 8 + j][n]);
        }
        unsigned short* p = Wct + (size_t)(n0 + n) * Kdim + k0 + koff;
        *(short8*)p = o0;
        *(short8*)(p + 8) = o1;
    } else {
        float v[16];
        #pragma unroll
        for (int m = 0; m < 16; m++) v[m] = Ls[koff + m][n];
        int h = (koff >> 4) & 1;
        int base32 = koff & ~31;
        unsigned short* p = W2tp + (size_t)(n0 + n) * Kdim + k0 + base32 + 4 * h;
        #pragma unroll
        for (int g2 = 0; g2 < 4; g2++) {
            uint2 o;
            o.x = packbf_rn(v[4*g2+1], v[4*g2+0]);
            o.y = packbf_rn(v[4*g2+3], v[4*g2+2]);
            *(uint2*)(p + 8 * g2) = o;       // dst u16 idx: base32 + 8*g2 + 4*h + r
        }
    }
}

// ---------------------------------------------------------------------------
// K1: MFMA attention, transpose-free via key permutation.
// kv holds CSCALE*cos (Q and K operands) so the QK^T MFMA result IS the
// exp2 argument -> v_exp_f32 with zero preceding muls. vtp holds raw cos
// (V operand), pi-permuted keys so the P^T B-frag is a lane-local pack.
// Ones-row at dim 8 gives the softmax denominator in the same C-frag.
// ---------------------------------------------------------------------------
__global__ __launch_bounds__(256) void attn_mfma_kernel(const float* __restrict__ x,
                                                        const float* __restrict__ phi,
                                                        unsigned short* __restrict__ attn_bf) {
    int head = blockIdx.x >> 2, qquad = blockIdx.x & 3;
    int b = head >> 6, hh = head & 63;

    __shared__ unsigned short kv[S * DK];       // 16 KB  [key][dk], scaled
    __shared__ unsigned short vtp[9][S + 8];    // 18.6 KB [dim0..7 + ones][perm key]

    float ph[DK];
    #pragma unroll
    for (int d = 0; d < DK; d++) ph[d] = phi[d];

    int tid = threadIdx.x;
    for (int r = tid; r < S; r += 256) {
        const float* xp = x + ((size_t)(b * S + r)) * E + hh * DK;
        float4 u = *(const float4*)xp;
        float4 v = *(const float4*)(xp + 4);
        float c[8] = {__cosf(u.x+ph[0]), __cosf(u.y+ph[1]), __cosf(u.z+ph[2]), __cosf(u.w+ph[3]),
                      __cosf(v.x+ph[4]), __cosf(v.y+ph[5]), __cosf(v.z+ph[6]), __cosf(v.w+ph[7])};
        unsigned* kp = (unsigned*)&kv[r * DK];
        #pragma unroll
        for (int d = 0; d < 4; d++)
            kp[d] = packbf_rn(c[2*d+1] * CSCALE, c[2*d] * CSCALE);
        int pr = pidx(r);
        #pragma unroll
        for (int d = 0; d < DK; d++) vtp[d][pr] = f2bf(c[d]);
        vtp[8][pr] = 0x3F80;                // 1.0 bf16 (denominator row)
    }
    __syncthreads();

    int w = tid >> 6, lane = tid & 63, col = lane & 15, g = lane >> 4;
    bool g0 = (g == 0);
    int q0 = qquad * 256 + w * 64;
    const short8 z8 = {0,0,0,0,0,0,0,0};
    const float4a zc = {0.f,0.f,0.f,0.f};

    short8 aq[4];                            // Q B-frags, 4 q-tiles of 16
    #pragma unroll
    for (int t = 0; t < 4; t++)
        aq[t] = g0 ? *(const short8*)&kv[(q0 + t*16 + col) * DK] : z8;

    float4a acc[4];
    #pragma unroll
    for (int t = 0; t < 4; t++) acc[t] = zc;

    int vrow = col < 8 ? col : 8;            // clamp: dims 9..15 get denom dups
    const unsigned short* vbase = &vtp[vrow][0];

    for (int kb = 0; kb < S; kb += 32) {
        short8 bk0 = g0 ? *(const short8*)&kv[(kb + col) * DK] : z8;
        short8 bk1 = g0 ? *(const short8*)&kv[(kb + 16 + col) * DK] : z8;
        short8 vf = *(const short8*)(vbase + kb + g * 8);
        #pragma unroll
        for (int t = 0; t < 4; t++) {
            float4a s0 = __builtin_amdgcn_mfma_f32_16x16x32_bf16(bk0, aq[t], zc, 0,0,0);
            float4a s1 = __builtin_amdgcn_mfma_f32_16x16x32_bf16(bk1, aq[t], zc, 0,0,0);
            F4 S0, S1; S0.v = s0; S1.v = s1;
            float e00 = EXP2F(S0.f[0]);
            float e01 = EXP2F(S0.f[1]);
            float e02 = EXP2F(S0.f[2]);
            float e03 = EXP2F(S0.f[3]);
            float e10 = EXP2F(S1.f[0]);
            float e11 = EXP2F(S1.f[1]);
            float e12 = EXP2F(S1.f[2]);
            float e13 = EXP2F(S1.f[3]);
            U8 pf;                           // lane-local P^T B-frag (pi-ordered keys)
            pf.u[0] = packbf(e01, e00);
            pf.u[1] = packbf(e03, e02);
            pf.u[2] = packbf(e11, e10);
            pf.u[3] = packbf(e13, e12);
            acc[t] = __builtin_amdgcn_mfma_f32_16x16x32_bf16(vf, pf.v, acc[t], 0,0,0);
        }
    }
    // acc[t]: O'[dim=4g+r][q=col]; denom = dim 8 = lane 32+col, reg 0
    #pragma unroll
    for (int t = 0; t < 4; t++) {
        F4 a; a.v = acc[t];
        float denom = __shfl(a.f[0], 32 + col);
        float inv = __builtin_amdgcn_rcpf(denom);
        if (g < 2) {
            int token = b * S + q0 + t * 16 + col;
            uint2 o;
            o.x = packbf_rn(a.f[1] * inv, a.f[0] * inv);
            o.y = packbf_rn(a.f[3] * inv, a.f[2] * inv);
            *(uint2*)&attn_bf[(size_t)token * E + hh * DK + g * 4] = o;
        }
    }
}

// ---------------------------------------------------------------------------
// K2: combine-heads GEMM via MFMA, no LDS, no barriers.
// Re-grid for latency hiding: wave tile 16m x 32n, grid (64,16) -> 4096
// waves = 4/SIMD (was 1/SIMD at grid (64,4)).
// ---------------------------------------------------------------------------
__global__ __launch_bounds__(256) void combine_mfma(const unsigned short* __restrict__ A,
                                                    const unsigned short* __restrict__ Bt,
                                                    const float* __restrict__ bias,
                                                    unsigned short* __restrict__ Cbf) {
    int tid = threadIdx.x;
    int w = tid >> 6, lane = tid & 63;
    int row = lane & 15, g = lane >> 4, g8 = g * 8;
    int m0 = blockIdx.x * 64, n0 = blockIdx.y * 32;
    int mbase = m0 + w * 16;

    float4a acc[2];
    acc[0] = 0.f; acc[1] = 0.f;

    const unsigned short* ap = A + (size_t)(mbase + row) * 512 + g8;
    for (int kb = 0; kb < 512; kb += 32) {
        short8 af = *(const short8*)(ap + kb);
        #pragma unroll
        for (int nt = 0; nt < 2; nt++) {
            short8 bf = *(const short8*)(Bt + (size_t)(n0 + nt * 16 + row) * 512 + kb + g8);
            acc[nt] = __builtin_amdgcn_mfma_f32_16x16x32_bf16(af, bf, acc[nt], 0, 0, 0);
        }
    }
    int crow = mbase + g * 4;
    #pragma unroll
    for (int nt = 0; nt < 2; nt++) {
        int col = n0 + nt * 16 + row;
        float bb = bias[col];
        #pragma unroll
        for (int r = 0; r < 4; r++)
            Cbf[(size_t)(crow + r) * 512 + col] = f2bf(acc[nt][r] + bb);
    }
}

// ---------------------------------------------------------------------------
// K4: FFN, transpose-free via the same pi trick.
// H^T = mfma(A=W1^T-frag, B=qout-frag) -> bias+relu -> lane-local pack
// (f-axis pi-permuted) -> OUT^T = mfma(A=W2tp-frag, B=H^T, acc).
// Re-grid: wave tile 16 tokens x 32 n, grid (64,16) -> 4096 waves = 4/SIMD.
// ---------------------------------------------------------------------------
__global__ __launch_bounds__(256) void ffn_mfma(const unsigned short* __restrict__ qbf,
                                                const unsigned short* __restrict__ W1tg,
                                                const float* __restrict__ b1,
                                                const unsigned short* __restrict__ W2tp,
                                                const float* __restrict__ b2,
                                                unsigned short* __restrict__ Cbf) {
    __shared__ unsigned short w1t[FFN * DK];   // 32 KB [f][i]
    __shared__ float b1s[FFN];                 // 8 KB
    int tid = threadIdx.x;
    for (int i = tid; i < FFN * DK / 8; i += 256)
        ((uint4*)w1t)[i] = ((const uint4*)W1tg)[i];
    for (int i = tid; i < FFN / 4; i += 256)
        ((float4*)b1s)[i] = ((const float4*)b1)[i];
    __syncthreads();

    int w = tid >> 6, lane = tid & 63, col = lane & 15, g = lane >> 4;
    bool g0 = (g == 0);
    int m0 = blockIdx.x * 64, n0 = blockIdx.y * 32;
    int mw = m0 + w * 16;
    const short8 z8 = {0,0,0,0,0,0,0,0};
    const float4a zc = {0.f,0.f,0.f,0.f};

    short8 qf = g0 ? *(const short8*)&qbf[(mw + col) * DK] : z8;

    float4a acc[2];
    acc[0] = zc; acc[1] = zc;
    float4 b2v[2];
    #pragma unroll
    for (int nt = 0; nt < 2; nt++) b2v[nt] = *(const float4*)&b2[n0 + nt*16 + 4*g];

    for (int kb = 0; kb < FFN; kb += 32) {
        short8 w1f0 = g0 ? *(const short8*)&w1t[(kb + col) * DK] : z8;
        short8 w1f1 = g0 ? *(const short8*)&w1t[(kb + 16 + col) * DK] : z8;
        float4a h0 = __builtin_amdgcn_mfma_f32_16x16x32_bf16(w1f0, qf, zc, 0,0,0);
        float4a h1 = __builtin_amdgcn_mfma_f32_16x16x32_bf16(w1f1, qf, zc, 0,0,0);
        float4 bb0 = *(const float4*)&b1s[kb + 4*g];          // f = kb+4g+r
        float4 bb1 = *(const float4*)&b1s[kb + 16 + 4*g];     // f = kb+16+4g+r
        F4 H0, H1; H0.v = h0; H1.v = h1;
        float e00 = fmaxf(H0.f[0] + bb0.x, 0.f);
        float e01 = fmaxf(H0.f[1] + bb0.y, 0.f);
        float e02 = fmaxf(H0.f[2] + bb0.z, 0.f);
        float e03 = fmaxf(H0.f[3] + bb0.w, 0.f);
        float e10 = fmaxf(H1.f[0] + bb1.x, 0.f);
        float e11 = fmaxf(H1.f[1] + bb1.y, 0.f);
        float e12 = fmaxf(H1.f[2] + bb1.z, 0.f);
        float e13 = fmaxf(H1.f[3] + bb1.w, 0.f);
        U8 pf;                               // H^T B-frag, pi-ordered f
        pf.u[0] = packbf(e01, e00);
        pf.u[1] = packbf(e03, e02);
        pf.u[2] = packbf(e11, e10);
        pf.u[3] = packbf(e13, e12);
        #pragma unroll
        for (int nt = 0; nt < 2; nt++) {
            short8 af = *(const short8*)&W2tp[(size_t)(n0 + nt*16 + col) * FFN + kb + g*8];
            acc[nt] = __builtin_amdgcn_mfma_f32_16x16x32_bf16(af, pf.v, acc[nt], 0,0,0);
        }
    }
    // acc[nt]: OUT^T[n_local=4g+r][token=col]
    #pragma unroll
    for (int nt = 0; nt < 2; nt++) {
        F4 a; a.v = acc[nt];
        float4 bb = b2v[nt];
        uint2 o;
        o.x = packbf_rn(a.f[1] + bb.y, a.f[0] + bb.x);
        o.y = packbf_rn(a.f[3] + bb.w, a.f[2] + bb.z);
        *(uint2*)&Cbf[(size_t)(mw + col) * E + n0 + nt * 16 + 4 * g] = o;
    }
}

// ---------------------------------------------------------------------------
// K3/K5: LayerNorm over E=512, residual bf16, float2-vectorized.
// Optional epilogue: qoutbf[t][i] = bf16(cos(y_i) * cos(theta_i)), i<8.
// ---------------------------------------------------------------------------
__global__ __launch_bounds__(256) void ln_kernel(const float* a,
                                                 const unsigned short* __restrict__ r,
                                                 const float* __restrict__ g,
                                                 const float* __restrict__ be,
                                                 float* out,
                                                 unsigned short* __restrict__ qoutbf,
                                                 const float* __restrict__ theta) {
    int t = blockIdx.x, tid = threadIdx.x;
    size_t base = (size_t)t * E;
    int e0 = tid * 2;
    float2 av = *(const float2*)&a[base + e0];
    unsigned rv = *(const unsigned*)&r[base + e0];
    float v0 = av.x + bf2f((unsigned short)(rv & 0xffff));
    float v1 = av.y + bf2f((unsigned short)(rv >> 16));
    float s  = v0 + v1;
    float sq = v0 * v0 + v1 * v1;
    #pragma unroll
    for (int off = 32; off > 0; off >>= 1) {
        s  += __shfl_down(s, off);
        sq += __shfl_down(sq, off);
    }
    __shared__ float ls[4], lq[4];
    int wave = tid >> 6, lane = tid & 63;
    if (lane == 0) { ls[wave] = s; lq[wave] = sq; }
    __syncthreads();
    if (tid == 0) {
        float SS = ls[0] + ls[1] + ls[2] + ls[3];
        float QQ = lq[0] + lq[1] + lq[2] + lq[3];
        float mu = SS * (1.f / E);
        float var = QQ * (1.f / E) - mu * mu;
        ls[0] = mu;
        lq[0] = rsqrtf(var + 1e-5f);
    }
    __syncthreads();
    float mu = ls[0], rstd = lq[0];
    float2 gv = *(const float2*)&g[e0];
    float2 bv = *(const float2*)&be[e0];
    float y0 = (v0 - mu) * rstd * gv.x + bv.x;
    float y1 = (v1 - mu) * rstd * gv.y + bv.y;
    *(float2*)&out[base + e0] = make_float2(y0, y1);
    if (qoutbf != nullptr && tid < 4) {
        float q0v = __cosf(y0) * __cosf(theta[e0]);
        float q1v = __cosf(y1) * __cosf(theta[e0 + 1]);
        *(unsigned*)&qoutbf[t * DK + e0] = packbf_rn(q1v, q0v);
    }
}

// ---------------------------------------------------------------------------
// launch — ws: proj_bf 4MB + Wct 0.5MB + W2tp 2MB + W1t 32KB + qoutbf 64KB
// = 6.59 MB (under the 8.13 MB proven-safe budget). d_out doubles as scratch:
// attn_bf (4MB bf16), then x1 (8MB fp32), LN2 in-place.
// ---------------------------------------------------------------------------
extern "C" void kernel_launch(void* const* d_in, const int* in_sizes, int n_in,
                              void* d_out, int out_size, void* d_ws, size_t ws_size,
                              hipStream_t stream) {
    const float* x     = (const float*)d_in[0];
    const float* phi   = (const float*)d_in[1];
    const float* Wc    = (const float*)d_in[2];
    const float* bc    = (const float*)d_in[3];
    const float* theta = (const float*)d_in[4];
    const float* W1    = (const float*)d_in[5];
    const float* b1    = (const float*)d_in[6];
    const float* W2    = (const float*)d_in[7];
    const float* b2    = (const float*)d_in[8];
    const float* g1    = (const float*)d_in[9];
    const float* be1   = (const float*)d_in[10];
    const float* g2    = (const float*)d_in[11];
    const float* be2   = (const float*)d_in[12];
    float* out = (float*)d_out;

    float* ws = (float*)d_ws;
    unsigned short* proj_bf = (unsigned short*)ws;                                // 4 MB
    unsigned short* Wct     = (unsigned short*)(ws + 1048576);                    // 0.5 MB
    unsigned short* W2tp    = (unsigned short*)(ws + 1048576 + 131072);           // 2 MB
    unsigned short* W1t     = (unsigned short*)(ws + 1048576 + 131072 + 524288);  // 32 KB
    unsigned short* qoutbf  = (unsigned short*)(ws + 1048576 + 131072 + 524288 + 8192); // 64 KB
    unsigned short* attn_bf = (unsigned short*)d_out;

    convert_kernel<<<321, 256, 0, stream>>>(Wc, W2, W1, Wct, W2tp, W1t);
    attn_mfma_kernel<<<B * H * 4, 256, 0, stream>>>(x, phi, attn_bf);
    combine_mfma<<<dim3(64, 16), 256, 0, stream>>>(attn_bf, Wct, bc, proj_bf);
    ln_kernel<<<BS, 256, 0, stream>>>(x, proj_bf, g1, be1, out, qoutbf, theta);
    ffn_mfma<<<dim3(64, 16), 256, 0, stream>>>(qoutbf, W1t, b1, W2tp, b2, proj_bf);
    ln_kernel<<<BS, 256, 0, stream>>>(out, proj_bf, g2, be2, out, nullptr, nullptr);
}

// Round 7
// 193.618 us; speedup vs baseline: 2.3880x; 1.1961x over previous
//
#include <hip/hip_runtime.h>
#include <hip/hip_bf16.h>
#include <math.h>

// Problem dims (fixed)
#define B 4
#define S 1024
#define E 512
#define H 64
#define DK 8
#define FFN 2048
#define BS (B*S)          // 4096 tokens

// kv pre-scale: CSCALE^2 = (1/sqrt(8)) * log2(e) so exp(score/sqrt(8)) = 2^(scaled score)
#define CSCALE 0.7141879f

#if __has_builtin(__builtin_amdgcn_exp2f)
#define EXP2F(x) __builtin_amdgcn_exp2f(x)
#else
#define EXP2F(x) exp2f(x)
#endif

typedef __attribute__((ext_vector_type(8))) short short8;   // 8 bf16 (4 VGPRs)
typedef __attribute__((ext_vector_type(4))) float float4a;  // MFMA C/D frag

union U8 { short8 v; unsigned u[4]; };
union F4 { float4a v; float f[4]; };

// fp32 -> bf16 round-to-nearest-even
__device__ __forceinline__ unsigned short f2bf(float f) {
    unsigned u = __builtin_bit_cast(unsigned, f);
    u = (u + 0x7fffu + ((u >> 16) & 1u)) >> 16;
    return (unsigned short)u;
}
__device__ __forceinline__ float bf2f(unsigned short h) {
    return __builtin_bit_cast(float, (unsigned)h << 16);
}
// one-op pack: (trunc_bf16(a) << 16) | trunc_bf16(b)
__device__ __forceinline__ unsigned packbf(float a, float b) {
    return __builtin_amdgcn_perm(__builtin_bit_cast(unsigned, a),
                                 __builtin_bit_cast(unsigned, b), 0x07060302u);
}
// rounded pack: (rn_bf16(a) << 16) | rn_bf16(b)
__device__ __forceinline__ unsigned packbf_rn(float a, float b) {
    return ((unsigned)f2bf(a) << 16) | f2bf(b);
}
// key permutation within 32-blocks (attention PV): frag pos g*8+4h+r <-> key 16h+4g+r
__device__ __forceinline__ int pidx(int k) {
    return (k & ~31) | (((k >> 2) & 3) << 3) | (((k >> 4) & 1) << 2) | (k & 3);
}

// ---------------------------------------------------------------------------
// K0: weight conversion to FRAG-MAJOR bf16 (each 1KB chunk = one wave's MFMA
// fragment, chunk[lane][j], so kernel loads are 16B/lane coalesced streams).
//  W2f: 32 ntile x 64 kb32 chunks; [g*16+col][j] = W2[kb+16*(j>>2)+4g+(j&3)][n]
//       (pi-permuted k to match the H^T fragment the ffn kernel builds)
//  Wcf: 32 ntile x 16 kb32 chunks; [g*16+col][j] = Wc[kb+g*8+j][n]  (direct)
//  W1f: 64 kb32 x 2 half chunks; g0: W1[j][f], g1 j0: b1[f], else 0
//       (bias folded into k-slot 8 of the H-MFMA)
// One thread per short8. 172032 threads = 672 blocks.
// ---------------------------------------------------------------------------
__global__ __launch_bounds__(256) void convert_kernel(const float* __restrict__ Wc,
                                                      const float* __restrict__ W2,
                                                      const float* __restrict__ W1,
                                                      const float* __restrict__ b1,
                                                      unsigned short* __restrict__ W2f,
                                                      unsigned short* __restrict__ Wcf,
                                                      unsigned short* __restrict__ W1f) {
    int idx = blockIdx.x * 256 + threadIdx.x;
    if (idx < 131072) {                       // W2f
        int lane = idx & 63, c = idx >> 6;
        int ntile = c >> 6, kb32 = c & 63;
        int g = lane >> 4, col = lane & 15;
        int n = ntile * 16 + col, kb = kb32 * 32;
        short8 o;
        #pragma unroll
        for (int j = 0; j < 8; j++) {
            int k = kb + 16 * (j >> 2) + 4 * g + (j & 3);
            o[j] = (short)f2bf(W2[(size_t)k * 512 + n]);
        }
        *(short8*)&W2f[(size_t)idx * 8] = o;
    } else if (idx < 163840) {                // Wcf
        int i2 = idx - 131072;
        int lane = i2 & 63, c = i2 >> 6;
        int ntile = c >> 4, kb32 = c & 15;
        int g = lane >> 4, col = lane & 15;
        int n = ntile * 16 + col, kb = kb32 * 32;
        short8 o;
        #pragma unroll
        for (int j = 0; j < 8; j++)
            o[j] = (short)f2bf(Wc[(size_t)(kb + g * 8 + j) * 512 + n]);
        *(short8*)&Wcf[(size_t)i2 * 8] = o;
    } else {                                  // W1f
        int i3 = idx - 163840;
        int lane = i3 & 63, c = i3 >> 6;      // c = kb32*2 + half
        int g = lane >> 4, col = lane & 15;
        int f = (c >> 1) * 32 + (c & 1) * 16 + col;
        short8 o = {0,0,0,0,0,0,0,0};
        if (g == 0) {
            #pragma unroll
            for (int j = 0; j < 8; j++) o[j] = (short)f2bf(W1[j * FFN + f]);
        } else if (g == 1) {
            o[0] = (short)f2bf(b1[f]);
        }
        *(short8*)&W1f[(size_t)i3 * 8] = o;
    }
}

// ---------------------------------------------------------------------------
// K1: MFMA attention (unchanged math from R6) writing FRAG-MAJOR output:
// Afrag chunk (kb32 = hh>>2, ttile = b*64+qquad*16+w*4+t), lane'=(hh&3)*16+col,
// j' = 4*g_a + r  -> combine's A-fragment loads become coalesced streams.
// ---------------------------------------------------------------------------
__global__ __launch_bounds__(256) void attn_mfma_kernel(const float* __restrict__ x,
                                                        const float* __restrict__ phi,
                                                        unsigned short* __restrict__ Afrag) {
    int head = blockIdx.x >> 2, qquad = blockIdx.x & 3;
    int b = head >> 6, hh = head & 63;

    __shared__ unsigned short kv[S * DK];       // 16 KB  [key][dk], scaled
    __shared__ unsigned short vtp[9][S + 8];    // 18.6 KB [dim0..7 + ones][perm key]

    float ph[DK];
    #pragma unroll
    for (int d = 0; d < DK; d++) ph[d] = phi[d];

    int tid = threadIdx.x;
    for (int r = tid; r < S; r += 256) {
        const float* xp = x + ((size_t)(b * S + r)) * E + hh * DK;
        float4 u = *(const float4*)xp;
        float4 v = *(const float4*)(xp + 4);
        float c[8] = {__cosf(u.x+ph[0]), __cosf(u.y+ph[1]), __cosf(u.z+ph[2]), __cosf(u.w+ph[3]),
                      __cosf(v.x+ph[4]), __cosf(v.y+ph[5]), __cosf(v.z+ph[6]), __cosf(v.w+ph[7])};
        unsigned* kp = (unsigned*)&kv[r * DK];
        #pragma unroll
        for (int d = 0; d < 4; d++)
            kp[d] = packbf_rn(c[2*d+1] * CSCALE, c[2*d] * CSCALE);
        int pr = pidx(r);
        #pragma unroll
        for (int d = 0; d < DK; d++) vtp[d][pr] = f2bf(c[d]);
        vtp[8][pr] = 0x3F80;                // 1.0 bf16 (denominator row)
    }
    __syncthreads();

    int w = tid >> 6, lane = tid & 63, col = lane & 15, g = lane >> 4;
    bool g0 = (g == 0);
    int q0 = qquad * 256 + w * 64;
    const short8 z8 = {0,0,0,0,0,0,0,0};
    const float4a zc = {0.f,0.f,0.f,0.f};

    short8 aq[4];                            // Q B-frags, 4 q-tiles of 16
    #pragma unroll
    for (int t = 0; t < 4; t++)
        aq[t] = g0 ? *(const short8*)&kv[(q0 + t*16 + col) * DK] : z8;

    float4a acc[4];
    #pragma unroll
    for (int t = 0; t < 4; t++) acc[t] = zc;

    int vrow = col < 8 ? col : 8;            // clamp: dims 9..15 get denom dups
    const unsigned short* vbase = &vtp[vrow][0];

    for (int kb = 0; kb < S; kb += 32) {
        short8 bk0 = g0 ? *(const short8*)&kv[(kb + col) * DK] : z8;
        short8 bk1 = g0 ? *(const short8*)&kv[(kb + 16 + col) * DK] : z8;
        short8 vf = *(const short8*)(vbase + kb + g * 8);
        #pragma unroll
        for (int t = 0; t < 4; t++) {
            float4a s0 = __builtin_amdgcn_mfma_f32_16x16x32_bf16(bk0, aq[t], zc, 0,0,0);
            float4a s1 = __builtin_amdgcn_mfma_f32_16x16x32_bf16(bk1, aq[t], zc, 0,0,0);
            F4 S0, S1; S0.v = s0; S1.v = s1;
            float e00 = EXP2F(S0.f[0]);
            float e01 = EXP2F(S0.f[1]);
            float e02 = EXP2F(S0.f[2]);
            float e03 = EXP2F(S0.f[3]);
            float e10 = EXP2F(S1.f[0]);
            float e11 = EXP2F(S1.f[1]);
            float e12 = EXP2F(S1.f[2]);
            float e13 = EXP2F(S1.f[3]);
            U8 pf;                           // lane-local P^T B-frag (pi-ordered keys)
            pf.u[0] = packbf(e01, e00);
            pf.u[1] = packbf(e03, e02);
            pf.u[2] = packbf(e11, e10);
            pf.u[3] = packbf(e13, e12);
            acc[t] = __builtin_amdgcn_mfma_f32_16x16x32_bf16(vf, pf.v, acc[t], 0,0,0);
        }
    }
    // acc[t]: O'[dim=4g+r][q=col]; denom = dim 8 = lane 32+col, reg 0
    int lp8 = ((hh & 3) * 16 + col) * 8;     // lane' * 8 (u16 units)
    #pragma unroll
    for (int t = 0; t < 4; t++) {
        F4 a; a.v = acc[t];
        float denom = __shfl(a.f[0], 32 + col);
        float inv = __builtin_amdgcn_rcpf(denom);
        if (g < 2) {
            int chunk = (hh >> 2) * 256 + ((b << 6) | (qquad << 4) | (w << 2) | t);
            uint2 o;
            o.x = packbf_rn(a.f[1] * inv, a.f[0] * inv);
            o.y = packbf_rn(a.f[3] * inv, a.f[2] * inv);
            *(uint2*)&Afrag[(size_t)chunk * 512 + lp8 + g * 4] = o;
        }
    }
}

// ---------------------------------------------------------------------------
// K2: combine-heads GEMM, all operands frag-major (coalesced 16B/lane loads).
// Wave = 16 tokens x 64 n; block = 4 waves = 64 tok x 64 n; grid (64,8).
// ---------------------------------------------------------------------------
__global__ __launch_bounds__(256) void combine_mfma(const unsigned short* __restrict__ Afrag,
                                                    const unsigned short* __restrict__ Wcf,
                                                    const float* __restrict__ bias,
                                                    unsigned short* __restrict__ Cbf) {
    int tid = threadIdx.x;
    int w = tid >> 6, lane = tid & 63;
    int col = lane & 15, g = lane >> 4;
    int ttile = blockIdx.x * 4 + w;
    int nt0 = blockIdx.y * 4;                // ntile base (64 n)
    const float4a zc = {0.f,0.f,0.f,0.f};

    float4a acc[4];
    #pragma unroll
    for (int nt = 0; nt < 4; nt++) acc[nt] = zc;

    for (int kb32 = 0; kb32 < 16; kb32++) {
        short8 af = *(const short8*)&Afrag[((size_t)(kb32 * 256 + ttile) * 64 + lane) * 8];
        #pragma unroll
        for (int nt = 0; nt < 4; nt++) {
            short8 bf = *(const short8*)&Wcf[((size_t)((nt0 + nt) * 16 + kb32) * 64 + lane) * 8];
            acc[nt] = __builtin_amdgcn_mfma_f32_16x16x32_bf16(af, bf, acc[nt], 0, 0, 0);
        }
    }
    // acc[nt]: D[tok=4g+r][n=col] (C layout: row=m=token, col=n)
    int crow = ttile * 16 + g * 4;
    #pragma unroll
    for (int nt = 0; nt < 4; nt++) {
        int n = nt0 * 16 + nt * 16 + col;
        float bb = bias[n];
        #pragma unroll
        for (int r = 0; r < 4; r++)
            Cbf[(size_t)(crow + r) * 512 + n] = f2bf(acc[nt][r] + bb);
    }
}

// ---------------------------------------------------------------------------
// K4: FFN, frag-major weights, bias folded into H-MFMA k-slot 8.
// Wave = 32 tokens (2 ttiles) x 32 n (2 nt); block = 4 waves = 128 tok x 32 n;
// grid (32,16) = 512 blocks. W1(+b1) staged once in LDS (64 KB, 2 blk/CU);
// K-loop barrier-free: 2 ds_reads + 2 coalesced global streams per step.
// ---------------------------------------------------------------------------
__global__ __launch_bounds__(256) void ffn_mfma(const unsigned short* __restrict__ qbf,
                                                const unsigned short* __restrict__ W1fg,
                                                const unsigned short* __restrict__ W2f,
                                                const float* __restrict__ b2,
                                                unsigned short* __restrict__ Cbf) {
    __shared__ unsigned short w1x[FFN * 16];   // 64 KB: [f][slot], slot8 = b1[f]
    int tid = threadIdx.x;
    #pragma unroll
    for (int i = 0; i < 16; i++) {
        int d = tid + i * 256;                 // d = f*2 + gg
        int f = d >> 1, gg = d & 1;
        int kb32 = f >> 5, half = (f >> 4) & 1, fc = f & 15;
        int src = ((kb32 * 2 + half) * 64 + gg * 16 + fc);
        *(short8*)&w1x[f * 16 + gg * 8] = *(const short8*)&W1fg[(size_t)src * 8];
    }
    __syncthreads();

    int w = tid >> 6, lane = tid & 63, col = lane & 15, g = lane >> 4;
    int mw = blockIdx.x * 128 + w * 32;
    int ntile0 = blockIdx.y * 2;
    const short8 z8 = {0,0,0,0,0,0,0,0};
    const short8 one8 = {(short)0x3F80,0,0,0,0,0,0,0};
    const float4a zc = {0.f,0.f,0.f,0.f};

    short8 qf[2];                              // B[k=qslot][n=tok]; slot8 = 1.0
    #pragma unroll
    for (int t = 0; t < 2; t++)
        qf[t] = (g == 0) ? *(const short8*)&qbf[(size_t)(mw + t * 16 + col) * 8]
                         : (g == 1 ? one8 : z8);

    float4a acc[2][2];
    acc[0][0] = zc; acc[0][1] = zc; acc[1][0] = zc; acc[1][1] = zc;

    const unsigned short* w2p0 = W2f + (size_t)(ntile0 * 64) * 512 + lane * 8;
    const unsigned short* w2p1 = W2f + (size_t)((ntile0 + 1) * 64) * 512 + lane * 8;

    for (int kb32 = 0; kb32 < 64; kb32++) {
        int kb = kb32 * 32;
        short8 w1f0 = (g < 2) ? *(const short8*)&w1x[(kb + col) * 16 + g * 8] : z8;
        short8 w1f1 = (g < 2) ? *(const short8*)&w1x[(kb + 16 + col) * 16 + g * 8] : z8;
        short8 af0 = *(const short8*)(w2p0 + (size_t)kb32 * 512);
        short8 af1 = *(const short8*)(w2p1 + (size_t)kb32 * 512);
        #pragma unroll
        for (int t = 0; t < 2; t++) {
            float4a h0 = __builtin_amdgcn_mfma_f32_16x16x32_bf16(w1f0, qf[t], zc, 0,0,0);
            float4a h1 = __builtin_amdgcn_mfma_f32_16x16x32_bf16(w1f1, qf[t], zc, 0,0,0);
            F4 H0, H1; H0.v = h0; H1.v = h1;
            float e00 = fmaxf(H0.f[0], 0.f);
            float e01 = fmaxf(H0.f[1], 0.f);
            float e02 = fmaxf(H0.f[2], 0.f);
            float e03 = fmaxf(H0.f[3], 0.f);
            float e10 = fmaxf(H1.f[0], 0.f);
            float e11 = fmaxf(H1.f[1], 0.f);
            float e12 = fmaxf(H1.f[2], 0.f);
            float e13 = fmaxf(H1.f[3], 0.f);
            U8 pf;                             // H^T B-frag, pi-ordered f
            pf.u[0] = packbf(e01, e00);
            pf.u[1] = packbf(e03, e02);
            pf.u[2] = packbf(e11, e10);
            pf.u[3] = packbf(e13, e12);
            acc[t][0] = __builtin_amdgcn_mfma_f32_16x16x32_bf16(af0, pf.v, acc[t][0], 0,0,0);
            acc[t][1] = __builtin_amdgcn_mfma_f32_16x16x32_bf16(af1, pf.v, acc[t][1], 0,0,0);
        }
    }
    // acc[t][nt]: OUT^T[n_loc=4g+r][tok=col]
    int n0 = ntile0 * 16;
    #pragma unroll
    for (int nt = 0; nt < 2; nt++) {
        float4 bb = *(const float4*)&b2[n0 + nt * 16 + 4 * g];
        #pragma unroll
        for (int t = 0; t < 2; t++) {
            F4 a; a.v = acc[t][nt];
            uint2 o;
            o.x = packbf_rn(a.f[1] + bb.y, a.f[0] + bb.x);
            o.y = packbf_rn(a.f[3] + bb.w, a.f[2] + bb.z);
            *(uint2*)&Cbf[(size_t)(mw + t * 16 + col) * 512 + n0 + nt * 16 + 4 * g] = o;
        }
    }
}

// ---------------------------------------------------------------------------
// K3/K5: LayerNorm over E=512, residual bf16, float2-vectorized.
// Optional epilogue: qoutbf[t][i] = bf16(cos(y_i) * cos(theta_i)), i<8.
// ---------------------------------------------------------------------------
__global__ __launch_bounds__(256) void ln_kernel(const float* a,
                                                 const unsigned short* __restrict__ r,
                                                 const float* __restrict__ g,
                                                 const float* __restrict__ be,
                                                 float* out,
                                                 unsigned short* __restrict__ qoutbf,
                                                 const float* __restrict__ theta) {
    int t = blockIdx.x, tid = threadIdx.x;
    size_t base = (size_t)t * E;
    int e0 = tid * 2;
    float2 av = *(const float2*)&a[base + e0];
    unsigned rv = *(const unsigned*)&r[base + e0];
    float v0 = av.x + bf2f((unsigned short)(rv & 0xffff));
    float v1 = av.y + bf2f((unsigned short)(rv >> 16));
    float s  = v0 + v1;
    float sq = v0 * v0 + v1 * v1;
    #pragma unroll
    for (int off = 32; off > 0; off >>= 1) {
        s  += __shfl_down(s, off);
        sq += __shfl_down(sq, off);
    }
    __shared__ float ls[4], lq[4];
    int wave = tid >> 6, lane = tid & 63;
    if (lane == 0) { ls[wave] = s; lq[wave] = sq; }
    __syncthreads();
    if (tid == 0) {
        float SS = ls[0] + ls[1] + ls[2] + ls[3];
        float QQ = lq[0] + lq[1] + lq[2] + lq[3];
        float mu = SS * (1.f / E);
        float var = QQ * (1.f / E) - mu * mu;
        ls[0] = mu;
        lq[0] = rsqrtf(var + 1e-5f);
    }
    __syncthreads();
    float mu = ls[0], rstd = lq[0];
    float2 gv = *(const float2*)&g[e0];
    float2 bv = *(const float2*)&be[e0];
    float y0 = (v0 - mu) * rstd * gv.x + bv.x;
    float y1 = (v1 - mu) * rstd * gv.y + bv.y;
    *(float2*)&out[base + e0] = make_float2(y0, y1);
    if (qoutbf != nullptr && tid < 4) {
        float q0v = __cosf(y0) * __cosf(theta[e0]);
        float q1v = __cosf(y1) * __cosf(theta[e0 + 1]);
        *(unsigned*)&qoutbf[t * DK + e0] = packbf_rn(q1v, q0v);
    }
}

// ---------------------------------------------------------------------------
// launch — ws: proj 4MB | W2f 2MB | Wcf 0.5MB | W1f 128KB | qoutbf 64KB
// = 6.69 MB (under the 8.13 MB proven-safe budget). d_out doubles as scratch:
// Afrag (4MB bf16), then x1 (8MB fp32, overwrites dead Afrag), LN2 in-place.
// ---------------------------------------------------------------------------
extern "C" void kernel_launch(void* const* d_in, const int* in_sizes, int n_in,
                              void* d_out, int out_size, void* d_ws, size_t ws_size,
                              hipStream_t stream) {
    const float* x     = (const float*)d_in[0];
    const float* phi   = (const float*)d_in[1];
    const float* Wc    = (const float*)d_in[2];
    const float* bc    = (const float*)d_in[3];
    const float* theta = (const float*)d_in[4];
    const float* W1    = (const float*)d_in[5];
    const float* b1    = (const float*)d_in[6];
    const float* W2    = (const float*)d_in[7];
    const float* b2    = (const float*)d_in[8];
    const float* g1    = (const float*)d_in[9];
    const float* be1   = (const float*)d_in[10];
    const float* g2    = (const float*)d_in[11];
    const float* be2   = (const float*)d_in[12];
    float* out = (float*)d_out;

    float* ws = (float*)d_ws;
    unsigned short* proj   = (unsigned short*)ws;                       // 4 MB
    unsigned short* W2f    = (unsigned short*)(ws + 1048576);           // 2 MB
    unsigned short* Wcf    = (unsigned short*)(ws + 1572864);           // 512 KB
    unsigned short* W1f    = (unsigned short*)(ws + 1703936);           // 128 KB
    unsigned short* qoutbf = (unsigned short*)(ws + 1736704);           // 64 KB
    unsigned short* Afrag  = (unsigned short*)d_out;                    // 4 MB (scratch)

    convert_kernel<<<672, 256, 0, stream>>>(Wc, W2, W1, b1, W2f, Wcf, W1f);
    attn_mfma_kernel<<<B * H * 4, 256, 0, stream>>>(x, phi, Afrag);
    combine_mfma<<<dim3(64, 8), 256, 0, stream>>>(Afrag, Wcf, bc, proj);
    ln_kernel<<<BS, 256, 0, stream>>>(x, proj, g1, be1, out, qoutbf, theta);
    ffn_mfma<<<dim3(32, 16), 256, 0, stream>>>(qoutbf, W1f, W2f, b2, proj);
    ln_kernel<<<BS, 256, 0, stream>>>(out, proj, g2, be2, out, nullptr, nullptr);
}

// Round 8
// 164.759 us; speedup vs baseline: 2.8063x; 1.1752x over previous
//
#include <hip/hip_runtime.h>
#include <hip/hip_bf16.h>
#include <math.h>

// Problem dims (fixed)
#define B 4
#define S 1024
#define E 512
#define H 64
#define DK 8
#define FFN 2048
#define BS (B*S)          // 4096 tokens

// kv pre-scale: CSCALE^2 = (1/sqrt(8)) * log2(e) so exp(score/sqrt(8)) = 2^(scaled score)
#define CSCALE 0.7141879f

#if __has_builtin(__builtin_amdgcn_exp2f)
#define EXP2F(x) __builtin_amdgcn_exp2f(x)
#else
#define EXP2F(x) exp2f(x)
#endif

typedef __attribute__((ext_vector_type(8))) short short8;   // 8 bf16 (4 VGPRs)
typedef __attribute__((ext_vector_type(4))) float float4a;  // MFMA C/D frag

union U8 { short8 v; unsigned u[4]; };
union F4 { float4a v; float f[4]; };

__device__ __forceinline__ unsigned short f2bf(float f) {
    unsigned u = __builtin_bit_cast(unsigned, f);
    u = (u + 0x7fffu + ((u >> 16) & 1u)) >> 16;
    return (unsigned short)u;
}
__device__ __forceinline__ float bf2f(unsigned short h) {
    return __builtin_bit_cast(float, (unsigned)h << 16);
}
// one-op pack: (trunc_bf16(a) << 16) | trunc_bf16(b)
__device__ __forceinline__ unsigned packbf(float a, float b) {
    return __builtin_amdgcn_perm(__builtin_bit_cast(unsigned, a),
                                 __builtin_bit_cast(unsigned, b), 0x07060302u);
}
__device__ __forceinline__ unsigned packbf_rn(float a, float b) {
    return ((unsigned)f2bf(a) << 16) | f2bf(b);
}
// key permutation within 32-blocks (attention PV): frag pos g*8+4h+r <-> key 16h+4g+r
__device__ __forceinline__ int pidx(int k) {
    return (k & ~31) | (((k >> 2) & 3) << 3) | (((k >> 4) & 1) << 2) | (k & 3);
}

// ---------------------------------------------------------------------------
// K1: [blocks 0..511] MFMA attention (512 thr = 8 waves, half-head each).
//     [blocks 512..847] weight conversion to frag-major bf16 (R7 layout).
// Attention: zero-row kv trick removes all per-step selects: g!=0 lanes read
// a zeroed LDS row (same-address broadcast) via precomputed base+stride.
// ---------------------------------------------------------------------------
__global__ __launch_bounds__(512) void attn_conv_kernel(const float* __restrict__ x,
                                                        const float* __restrict__ phi,
                                                        const float* __restrict__ Wc,
                                                        const float* __restrict__ W2,
                                                        const float* __restrict__ W1,
                                                        const float* __restrict__ b1,
                                                        unsigned short* __restrict__ Afrag,
                                                        unsigned short* __restrict__ W2f,
                                                        unsigned short* __restrict__ Wcf,
                                                        unsigned short* __restrict__ W1f) {
    __shared__ unsigned short kv[(S + 16) * DK];   // 16.25 KB, rows S..S+15 zero
    __shared__ unsigned short vtp[9][S + 8];       // 18.6 KB [dim0..7 + ones][perm key]
    int bid = blockIdx.x;
    int tid = threadIdx.x;

    if (bid >= 512) {                               // ---- convert part ----
        int idx = (bid - 512) * 512 + tid;
        if (idx < 131072) {                         // W2f (pi-permuted k)
            int lane = idx & 63, c = idx >> 6;
            int ntile = c >> 6, kb32 = c & 63;
            int g = lane >> 4, col = lane & 15;
            int n = ntile * 16 + col, kb = kb32 * 32;
            short8 o;
            #pragma unroll
            for (int j = 0; j < 8; j++) {
                int k = kb + 16 * (j >> 2) + 4 * g + (j & 3);
                o[j] = (short)f2bf(W2[(size_t)k * 512 + n]);
            }
            *(short8*)&W2f[(size_t)idx * 8] = o;
        } else if (idx < 163840) {                  // Wcf (direct frag order)
            int i2 = idx - 131072;
            int lane = i2 & 63, c = i2 >> 6;
            int ntile = c >> 4, kb32 = c & 15;
            int g = lane >> 4, col = lane & 15;
            int n = ntile * 16 + col, kb = kb32 * 32;
            short8 o;
            #pragma unroll
            for (int j = 0; j < 8; j++)
                o[j] = (short)f2bf(Wc[(size_t)(kb + g * 8 + j) * 512 + n]);
            *(short8*)&Wcf[(size_t)i2 * 8] = o;
        } else {                                    // W1f (b1 folded at slot 8)
            int i3 = idx - 163840;
            int lane = i3 & 63, c = i3 >> 6;
            int g = lane >> 4, col = lane & 15;
            int f = (c >> 1) * 32 + (c & 1) * 16 + col;
            short8 o = {0,0,0,0,0,0,0,0};
            if (g == 0) {
                #pragma unroll
                for (int j = 0; j < 8; j++) o[j] = (short)f2bf(W1[j * FFN + f]);
            } else if (g == 1) {
                o[0] = (short)f2bf(b1[f]);
            }
            *(short8*)&W1f[(size_t)i3 * 8] = o;
        }
        return;
    }

    // ---- attention part ----
    int head = bid >> 1, qhalf = bid & 1;
    int b = head >> 6, hh = head & 63;

    float ph[DK];
    #pragma unroll
    for (int d = 0; d < DK; d++) ph[d] = phi[d];

    const short8 z8 = {0,0,0,0,0,0,0,0};
    for (int r = tid; r < S; r += 512) {
        const float* xp = x + ((size_t)(b * S + r)) * E + hh * DK;
        float4 u = *(const float4*)xp;
        float4 v = *(const float4*)(xp + 4);
        float c[8] = {__cosf(u.x+ph[0]), __cosf(u.y+ph[1]), __cosf(u.z+ph[2]), __cosf(u.w+ph[3]),
                      __cosf(v.x+ph[4]), __cosf(v.y+ph[5]), __cosf(v.z+ph[6]), __cosf(v.w+ph[7])};
        unsigned* kp = (unsigned*)&kv[r * DK];
        #pragma unroll
        for (int d = 0; d < 4; d++)
            kp[d] = packbf_rn(c[2*d+1] * CSCALE, c[2*d] * CSCALE);
        int pr = pidx(r);
        #pragma unroll
        for (int d = 0; d < DK; d++) vtp[d][pr] = f2bf(c[d]);
        vtp[8][pr] = 0x3F80;                // 1.0 bf16 (denominator row)
    }
    if (tid < 16) *(short8*)&kv[(S + tid) * DK] = z8;   // zero rows
    __syncthreads();

    int w = tid >> 6, lane = tid & 63, col = lane & 15, g = lane >> 4;
    bool g0 = (g == 0);
    int q0 = qhalf * 512 + w * 64;
    const float4a zc = {0.f,0.f,0.f,0.f};

    short8 aq[4];                            // Q B-frags, 4 q-tiles of 16
    #pragma unroll
    for (int t = 0; t < 4; t++)
        aq[t] = g0 ? *(const short8*)&kv[(q0 + t*16 + col) * DK] : z8;

    float4a acc[4];
    #pragma unroll
    for (int t = 0; t < 4; t++) acc[t] = zc;

    int vrow = col < 8 ? col : 8;            // clamp: dims 9..15 get denom dups
    const unsigned short* vbase = &vtp[vrow][0];

    // zero-row pointer trick: g!=0 lanes stay parked on the zero row
    int off0 = g0 ? col * DK : S * DK;
    int off1 = g0 ? (16 + col) * DK : S * DK;
    int stepo = g0 ? 32 * DK : 0;

    for (int kb = 0; kb < S; kb += 32) {
        short8 bk0 = *(const short8*)&kv[off0];
        short8 bk1 = *(const short8*)&kv[off1];
        off0 += stepo; off1 += stepo;
        short8 vf = *(const short8*)(vbase + kb + g * 8);
        #pragma unroll
        for (int t = 0; t < 4; t++) {
            float4a s0 = __builtin_amdgcn_mfma_f32_16x16x32_bf16(bk0, aq[t], zc, 0,0,0);
            float4a s1 = __builtin_amdgcn_mfma_f32_16x16x32_bf16(bk1, aq[t], zc, 0,0,0);
            F4 S0, S1; S0.v = s0; S1.v = s1;
            float e00 = EXP2F(S0.f[0]);
            float e01 = EXP2F(S0.f[1]);
            float e02 = EXP2F(S0.f[2]);
            float e03 = EXP2F(S0.f[3]);
            float e10 = EXP2F(S1.f[0]);
            float e11 = EXP2F(S1.f[1]);
            float e12 = EXP2F(S1.f[2]);
            float e13 = EXP2F(S1.f[3]);
            U8 pf;                           // lane-local P^T B-frag (pi-ordered keys)
            pf.u[0] = packbf(e01, e00);
            pf.u[1] = packbf(e03, e02);
            pf.u[2] = packbf(e11, e10);
            pf.u[3] = packbf(e13, e12);
            acc[t] = __builtin_amdgcn_mfma_f32_16x16x32_bf16(vf, pf.v, acc[t], 0,0,0);
        }
    }
    // acc[t]: O'[dim=4g+r][q=col]; denom = dim 8 = lane 32+col, reg 0
    int lp8 = ((hh & 3) * 16 + col) * 8;     // lane' * 8 (u16 units)
    #pragma unroll
    for (int t = 0; t < 4; t++) {
        F4 a; a.v = acc[t];
        float denom = __shfl(a.f[0], 32 + col);
        float inv = __builtin_amdgcn_rcpf(denom);
        if (g < 2) {
            int chunk = (hh >> 2) * 256 + ((b << 6) | (qhalf << 5) | (w << 2) | t);
            uint2 o;
            o.x = packbf_rn(a.f[1] * inv, a.f[0] * inv);
            o.y = packbf_rn(a.f[3] * inv, a.f[2] * inv);
            *(uint2*)&Afrag[(size_t)chunk * 512 + lp8 + g * 4] = o;
        }
    }
}

// ---------------------------------------------------------------------------
// K2: combine-heads GEMM + fused LN1 + qout. Block = 16 tokens x full 512 n
// (8 waves x 4 ntiles). A-tile (16 KB) staged in LDS; C goes to LDS (fp32,
// +bc), then in-block LN over full rows, write x1 (fp32, d_out) and qoutbf.
// ---------------------------------------------------------------------------
__global__ __launch_bounds__(512) void combine_ln1(const unsigned short* __restrict__ Afrag,
                                                   const unsigned short* __restrict__ Wcf,
                                                   const float* __restrict__ bc,
                                                   const float* __restrict__ x,
                                                   const float* __restrict__ g1,
                                                   const float* __restrict__ be1,
                                                   float* __restrict__ x1out,
                                                   unsigned short* __restrict__ qoutbf,
                                                   const float* __restrict__ theta) {
    __shared__ unsigned short As[16 * 64 * 8];      // 16 KB: A-frag chunks kb32 0..15
    __shared__ float xout[16][516];                 // 33 KB: C rows (+pad 4)
    int tt = blockIdx.x;                            // token tile 0..255
    int tid = threadIdx.x;

    for (int i = tid; i < 1024; i += 512)
        *(short8*)&As[i * 8] =
            *(const short8*)&Afrag[((size_t)((i >> 6) * 256 + tt) * 64 + (i & 63)) * 8];
    __syncthreads();

    int w = tid >> 6, lane = tid & 63, col = lane & 15, g = lane >> 4;
    const float4a zc = {0.f,0.f,0.f,0.f};
    float4a acc[4];
    #pragma unroll
    for (int nt = 0; nt < 4; nt++) acc[nt] = zc;

    for (int kb32 = 0; kb32 < 16; kb32++) {
        short8 af = *(const short8*)&As[(kb32 * 64 + lane) * 8];
        #pragma unroll
        for (int nt = 0; nt < 4; nt++) {
            short8 bf = *(const short8*)&Wcf[((size_t)((w * 4 + nt) * 16 + kb32) * 64 + lane) * 8];
            acc[nt] = __builtin_amdgcn_mfma_f32_16x16x32_bf16(af, bf, acc[nt], 0, 0, 0);
        }
    }
    // acc[nt][r] = OUT[token-local = g*4+r][n = w*64 + nt*16 + col]
    #pragma unroll
    for (int nt = 0; nt < 4; nt++) {
        int n = w * 64 + nt * 16 + col;
        float bb = bc[n];
        #pragma unroll
        for (int r = 0; r < 4; r++)
            xout[g * 4 + r][n] = acc[nt][r] + bb;
    }
    __syncthreads();

    // LN phase: wave w handles tokens 2w, 2w+1 (32 lanes each, 16 elems/lane)
    int hl = lane >> 5, l = lane & 31;
    int token = w * 2 + hl;
    int e0 = l * 16;
    size_t grow = ((size_t)tt * 16 + token) * 512;
    float v[16];
    float s = 0.f, sq = 0.f;
    #pragma unroll
    for (int u = 0; u < 4; u++) {
        float4 xv = *(const float4*)&x[grow + e0 + u * 4];
        float4 pv = *(const float4*)&xout[token][e0 + u * 4];
        float a0 = xv.x + pv.x, a1 = xv.y + pv.y, a2 = xv.z + pv.z, a3 = xv.w + pv.w;
        v[u*4] = a0; v[u*4+1] = a1; v[u*4+2] = a2; v[u*4+3] = a3;
        s += a0 + a1 + a2 + a3;
        sq += a0*a0 + a1*a1 + a2*a2 + a3*a3;
    }
    #pragma unroll
    for (int off = 1; off <= 16; off <<= 1) {
        s  += __shfl_xor(s, off);
        sq += __shfl_xor(sq, off);
    }
    float mu = s * (1.f / 512.f);
    float var = sq * (1.f / 512.f) - mu * mu;
    float rstd = rsqrtf(var + 1e-5f);
    float y[16];
    #pragma unroll
    for (int u = 0; u < 4; u++) {
        float4 gv = *(const float4*)&g1[e0 + u * 4];
        float4 bv = *(const float4*)&be1[e0 + u * 4];
        y[u*4]   = (v[u*4]   - mu) * rstd * gv.x + bv.x;
        y[u*4+1] = (v[u*4+1] - mu) * rstd * gv.y + bv.y;
        y[u*4+2] = (v[u*4+2] - mu) * rstd * gv.z + bv.z;
        y[u*4+3] = (v[u*4+3] - mu) * rstd * gv.w + bv.w;
        float4 o = make_float4(y[u*4], y[u*4+1], y[u*4+2], y[u*4+3]);
        *(float4*)&x1out[grow + e0 + u * 4] = o;
    }
    if (l == 0) {                         // qout from y[0..7]
        U8 q;
        q.u[0] = packbf_rn(__cosf(y[1]) * __cosf(theta[1]), __cosf(y[0]) * __cosf(theta[0]));
        q.u[1] = packbf_rn(__cosf(y[3]) * __cosf(theta[3]), __cosf(y[2]) * __cosf(theta[2]));
        q.u[2] = packbf_rn(__cosf(y[5]) * __cosf(theta[5]), __cosf(y[4]) * __cosf(theta[4]));
        q.u[3] = packbf_rn(__cosf(y[7]) * __cosf(theta[7]), __cosf(y[6]) * __cosf(theta[6]));
        *(short8*)&qoutbf[((size_t)tt * 16 + token) * 8] = q.v;
    }
}

// ---------------------------------------------------------------------------
// K3: FFN, 512-thr blocks (16 waves/CU). Frag-major weights, b1 folded into
// H-MFMA k-slot 8. Wave = 32 tokens x 32 n; block = 256 tok x 32 n.
// ---------------------------------------------------------------------------
__global__ __launch_bounds__(512) void ffn_mfma(const unsigned short* __restrict__ qbf,
                                                const unsigned short* __restrict__ W1fg,
                                                const unsigned short* __restrict__ W2f,
                                                const float* __restrict__ b2,
                                                unsigned short* __restrict__ Cbf) {
    __shared__ unsigned short w1x[FFN * 16];   // 64 KB: [f][slot], slot8 = b1[f]
    int tid = threadIdx.x;
    #pragma unroll
    for (int i = 0; i < 8; i++) {
        int d = tid + i * 512;                 // d = f*2 + gg
        int f = d >> 1, gg = d & 1;
        int kb32 = f >> 5, half = (f >> 4) & 1, fc = f & 15;
        int src = ((kb32 * 2 + half) * 64 + gg * 16 + fc);
        *(short8*)&w1x[f * 16 + gg * 8] = *(const short8*)&W1fg[(size_t)src * 8];
    }
    __syncthreads();

    int w = tid >> 6, lane = tid & 63, col = lane & 15, g = lane >> 4;
    int mw = blockIdx.x * 256 + w * 32;
    int ntile0 = blockIdx.y * 2;
    const short8 z8 = {0,0,0,0,0,0,0,0};
    const short8 one8 = {(short)0x3F80,0,0,0,0,0,0,0};
    const float4a zc = {0.f,0.f,0.f,0.f};

    short8 qf[2];                              // B[k=qslot][n=tok]; slot8 = 1.0
    #pragma unroll
    for (int t = 0; t < 2; t++)
        qf[t] = (g == 0) ? *(const short8*)&qbf[(size_t)(mw + t * 16 + col) * 8]
                         : (g == 1 ? one8 : z8);

    float4a acc[2][2];
    acc[0][0] = zc; acc[0][1] = zc; acc[1][0] = zc; acc[1][1] = zc;

    const unsigned short* w2p0 = W2f + (size_t)(ntile0 * 64) * 512 + lane * 8;
    const unsigned short* w2p1 = W2f + (size_t)((ntile0 + 1) * 64) * 512 + lane * 8;

    for (int kb32 = 0; kb32 < 64; kb32++) {
        int kb = kb32 * 32;
        short8 w1f0 = (g < 2) ? *(const short8*)&w1x[(kb + col) * 16 + g * 8] : z8;
        short8 w1f1 = (g < 2) ? *(const short8*)&w1x[(kb + 16 + col) * 16 + g * 8] : z8;
        short8 af0 = *(const short8*)(w2p0 + (size_t)kb32 * 512);
        short8 af1 = *(const short8*)(w2p1 + (size_t)kb32 * 512);
        #pragma unroll
        for (int t = 0; t < 2; t++) {
            float4a h0 = __builtin_amdgcn_mfma_f32_16x16x32_bf16(w1f0, qf[t], zc, 0,0,0);
            float4a h1 = __builtin_amdgcn_mfma_f32_16x16x32_bf16(w1f1, qf[t], zc, 0,0,0);
            F4 H0, H1; H0.v = h0; H1.v = h1;
            float e00 = fmaxf(H0.f[0], 0.f);
            float e01 = fmaxf(H0.f[1], 0.f);
            float e02 = fmaxf(H0.f[2], 0.f);
            float e03 = fmaxf(H0.f[3], 0.f);
            float e10 = fmaxf(H1.f[0], 0.f);
            float e11 = fmaxf(H1.f[1], 0.f);
            float e12 = fmaxf(H1.f[2], 0.f);
            float e13 = fmaxf(H1.f[3], 0.f);
            U8 pf;                             // H^T B-frag, pi-ordered f
            pf.u[0] = packbf(e01, e00);
            pf.u[1] = packbf(e03, e02);
            pf.u[2] = packbf(e11, e10);
            pf.u[3] = packbf(e13, e12);
            acc[t][0] = __builtin_amdgcn_mfma_f32_16x16x32_bf16(af0, pf.v, acc[t][0], 0,0,0);
            acc[t][1] = __builtin_amdgcn_mfma_f32_16x16x32_bf16(af1, pf.v, acc[t][1], 0,0,0);
        }
    }
    int n0 = ntile0 * 16;
    #pragma unroll
    for (int nt = 0; nt < 2; nt++) {
        float4 bb = *(const float4*)&b2[n0 + nt * 16 + 4 * g];
        #pragma unroll
        for (int t = 0; t < 2; t++) {
            F4 a; a.v = acc[t][nt];
            uint2 o;
            o.x = packbf_rn(a.f[1] + bb.y, a.f[0] + bb.x);
            o.y = packbf_rn(a.f[3] + bb.w, a.f[2] + bb.z);
            *(uint2*)&Cbf[(size_t)(mw + t * 16 + col) * 512 + n0 + nt * 16 + 4 * g] = o;
        }
    }
}

// ---------------------------------------------------------------------------
// K4: final LayerNorm (x1 fp32 + ffn_out bf16), in-place on d_out.
// ---------------------------------------------------------------------------
__global__ __launch_bounds__(256) void ln_kernel(const float* a,
                                                 const unsigned short* __restrict__ r,
                                                 const float* __restrict__ g,
                                                 const float* __restrict__ be,
                                                 float* out) {
    int t = blockIdx.x, tid = threadIdx.x;
    size_t base = (size_t)t * E;
    int e0 = tid * 2;
    float2 av = *(const float2*)&a[base + e0];
    unsigned rv = *(const unsigned*)&r[base + e0];
    float v0 = av.x + bf2f((unsigned short)(rv & 0xffff));
    float v1 = av.y + bf2f((unsigned short)(rv >> 16));
    float s  = v0 + v1;
    float sq = v0 * v0 + v1 * v1;
    #pragma unroll
    for (int off = 32; off > 0; off >>= 1) {
        s  += __shfl_down(s, off);
        sq += __shfl_down(sq, off);
    }
    __shared__ float ls[4], lq[4];
    int wave = tid >> 6, lane = tid & 63;
    if (lane == 0) { ls[wave] = s; lq[wave] = sq; }
    __syncthreads();
    if (tid == 0) {
        float SS = ls[0] + ls[1] + ls[2] + ls[3];
        float QQ = lq[0] + lq[1] + lq[2] + lq[3];
        float mu = SS * (1.f / E);
        float var = QQ * (1.f / E) - mu * mu;
        ls[0] = mu;
        lq[0] = rsqrtf(var + 1e-5f);
    }
    __syncthreads();
    float mu = ls[0], rstd = lq[0];
    float2 gv = *(const float2*)&g[e0];
    float2 bv = *(const float2*)&be[e0];
    float y0 = (v0 - mu) * rstd * gv.x + bv.x;
    float y1 = (v1 - mu) * rstd * gv.y + bv.y;
    *(float2*)&out[base + e0] = make_float2(y0, y1);
}

// ---------------------------------------------------------------------------
// launch — 4 kernels. ws: Afrag/ffn_out 4MB | W2f 2MB | Wcf 0.5MB | W1f 128KB
// | qoutbf 64KB = 6.7 MB (under proven 8.13 MB). d_out holds x1 fp32 then
// final LN2 in-place.
// ---------------------------------------------------------------------------
extern "C" void kernel_launch(void* const* d_in, const int* in_sizes, int n_in,
                              void* d_out, int out_size, void* d_ws, size_t ws_size,
                              hipStream_t stream) {
    const float* x     = (const float*)d_in[0];
    const float* phi   = (const float*)d_in[1];
    const float* Wc    = (const float*)d_in[2];
    const float* bc    = (const float*)d_in[3];
    const float* theta = (const float*)d_in[4];
    const float* W1    = (const float*)d_in[5];
    const float* b1    = (const float*)d_in[6];
    const float* W2    = (const float*)d_in[7];
    const float* b2    = (const float*)d_in[8];
    const float* g1    = (const float*)d_in[9];
    const float* be1   = (const float*)d_in[10];
    const float* g2    = (const float*)d_in[11];
    const float* be2   = (const float*)d_in[12];
    float* out = (float*)d_out;

    float* ws = (float*)d_ws;
    unsigned short* Afrag  = (unsigned short*)ws;                       // 4 MB (also ffn_out)
    unsigned short* W2f    = (unsigned short*)(ws + 1048576);           // 2 MB
    unsigned short* Wcf    = (unsigned short*)(ws + 1572864);           // 512 KB
    unsigned short* W1f    = (unsigned short*)(ws + 1703936);           // 128 KB
    unsigned short* qoutbf = (unsigned short*)(ws + 1736704);           // 64 KB

    attn_conv_kernel<<<848, 512, 0, stream>>>(x, phi, Wc, W2, W1, b1,
                                              Afrag, W2f, Wcf, W1f);
    combine_ln1<<<256, 512, 0, stream>>>(Afrag, Wcf, bc, x, g1, be1,
                                         out, qoutbf, theta);
    ffn_mfma<<<dim3(16, 16), 512, 0, stream>>>(qoutbf, W1f, W2f, b2, Afrag);
    ln_kernel<<<BS, 256, 0, stream>>>(out, Afrag, g2, be2, out);
}